// Round 3
// baseline (7163.137 us; speedup 1.0000x reference)
//
#include <hip/hip_runtime.h>
#include <hip/hip_bf16.h>
#include <math.h>
#include <type_traits>

typedef __hip_bfloat16 bf16;

#define Bb 16
#define Cch 512
#define Ss 1024          // H*W = 32*32
#define NHh 8
#define DHh 64
#define CPG 64           // channels per group (512/8)
#define EPSV 1e-5f
#define R_TOTAL (Bb*Ss)  // 16384

// ---------------- GroupNorm: per-(b,g) stats ----------------
__global__ __launch_bounds__(256) void gn_stats(const float* __restrict__ x,
                                                float* __restrict__ stats) {
    int bg = blockIdx.x;               // 0..127  (b*8+g)
    int b = bg >> 3, g = bg & 7;
    const float* base = x + ((size_t)b * Cch + (size_t)g * CPG) * Ss;
    float s = 0.f, ss = 0.f;
    for (int i = threadIdx.x; i < CPG * Ss; i += 256) {
        float v = base[i];
        s += v; ss += v * v;
    }
    for (int o = 32; o > 0; o >>= 1) { s += __shfl_down(s, o); ss += __shfl_down(ss, o); }
    __shared__ float red[2][4];
    int wid = threadIdx.x >> 6, lane = threadIdx.x & 63;
    if (lane == 0) { red[0][wid] = s; red[1][wid] = ss; }
    __syncthreads();
    if (threadIdx.x == 0) {
        float S1 = red[0][0] + red[0][1] + red[0][2] + red[0][3];
        float S2 = red[1][0] + red[1][1] + red[1][2] + red[1][3];
        const float inv_n = 1.0f / (CPG * Ss);
        float mu = S1 * inv_n;
        float var = S2 * inv_n - mu * mu;
        stats[bg * 2]     = mu;
        stats[bg * 2 + 1] = rsqrtf(var + EPSV);
    }
}

// ---------------- GroupNorm apply + transpose (B,C,S)->(B,S,C) ----------------
__global__ __launch_bounds__(256) void gn_apply_t(const float* __restrict__ x,
                                                  const float* __restrict__ stats,
                                                  const float* __restrict__ gw,
                                                  const float* __restrict__ gb,
                                                  float* __restrict__ ht) {
    __shared__ float tile[32][33];
    int b  = blockIdx.z;
    int c0 = blockIdx.y * 32;
    int s0 = blockIdx.x * 32;
    int tx = threadIdx.x, ty = threadIdx.y;
#pragma unroll
    for (int i = 0; i < 4; i++) {
        int c = c0 + ty + i * 8;
        int g = c >> 6;
        float mu = stats[(b * 8 + g) * 2];
        float rs = stats[(b * 8 + g) * 2 + 1];
        float v = x[((size_t)b * Cch + c) * Ss + s0 + tx];
        tile[ty + i * 8][tx] = (v - mu) * rs * gw[c] + gb[c];
    }
    __syncthreads();
#pragma unroll
    for (int i = 0; i < 4; i++) {
        int s = s0 + ty + i * 8;
        ht[((size_t)b * Ss + s) * Cch + c0 + tx] = tile[tx][ty + i * 8];
    }
}

// ---------------- 512x512 transpose (for pin_w, pout_w) ----------------
__global__ __launch_bounds__(256) void transpose512(const float* __restrict__ in,
                                                    float* __restrict__ outp) {
    __shared__ float tile[32][33];
    int c0 = blockIdx.x * 32, r0 = blockIdx.y * 32;
    int tx = threadIdx.x, ty = threadIdx.y;
#pragma unroll
    for (int i = 0; i < 4; i++)
        tile[ty + i * 8][tx] = in[(size_t)(r0 + ty + i * 8) * 512 + c0 + tx];
    __syncthreads();
#pragma unroll
    for (int i = 0; i < 4; i++)
        outp[(size_t)(c0 + ty + i * 8) * 512 + r0 + tx] = tile[tx][ty + i * 8];
}

// ---------------- LayerNorm over rows of (R,512) ----------------
__global__ __launch_bounds__(256) void layer_norm_rows(const float* __restrict__ in,
                                                       const float* __restrict__ w,
                                                       const float* __restrict__ bb,
                                                       float* __restrict__ outp) {
    int row = blockIdx.x;
    const float* p = in + (size_t)row * Cch;
    float v0 = p[threadIdx.x], v1 = p[threadIdx.x + 256];
    float s = v0 + v1, ss = v0 * v0 + v1 * v1;
    for (int o = 32; o > 0; o >>= 1) { s += __shfl_down(s, o); ss += __shfl_down(ss, o); }
    __shared__ float red[2][4];
    __shared__ float mu_s, rs_s;
    int wid = threadIdx.x >> 6, lane = threadIdx.x & 63;
    if (lane == 0) { red[0][wid] = s; red[1][wid] = ss; }
    __syncthreads();
    if (threadIdx.x == 0) {
        float S1 = red[0][0] + red[0][1] + red[0][2] + red[0][3];
        float S2 = red[1][0] + red[1][1] + red[1][2] + red[1][3];
        float mu = S1 * (1.0f / Cch);
        float var = S2 * (1.0f / Cch) - mu * mu;
        mu_s = mu; rs_s = rsqrtf(var + EPSV);
    }
    __syncthreads();
    float mu = mu_s, rs = rs_s;
    outp[(size_t)row * Cch + threadIdx.x]       = (v0 - mu) * rs * w[threadIdx.x] + bb[threadIdx.x];
    outp[(size_t)row * Cch + threadIdx.x + 256] = (v1 - mu) * rs * w[threadIdx.x + 256] + bb[threadIdx.x + 256];
}

// ---------------- Generic SGEMM: out(RxN) = A(RxK) @ B(KxN) [+bias][+res] ----------------
// EPI: 0 = none, 1 = +bias, 2 = +bias +res (res may alias out; in-place safe)
template<typename AT, int EPI>
__global__ __launch_bounds__(256) void gemm128(const AT* __restrict__ A,
                                               const float* __restrict__ Bm,
                                               const float* __restrict__ bias,
                                               const float* __restrict__ res,
                                               float* __restrict__ outp,
                                               int K, int N) {
    __shared__ float As[8][128];
    __shared__ float Bs[8][132];
    int m0 = blockIdx.y * 128;
    int n0 = blockIdx.x * 128;
    int tid = threadIdx.x;
    int tc = tid & 15, tr = tid >> 4;

    float acc[8][8];
#pragma unroll
    for (int i = 0; i < 8; i++)
#pragma unroll
        for (int j = 0; j < 8; j++) acc[i][j] = 0.f;

    int arow = tid >> 1, ak4 = (tid & 1) * 4;
    int bk = tid >> 5, bn4 = (tid & 31) * 4;

    for (int kt = 0; kt < K; kt += 8) {
        __syncthreads();
        // load A tile 128x8 (transposed into [k][m])
        if constexpr (std::is_same<AT, float>::value) {
            float4 t4 = *(const float4*)&A[(size_t)(m0 + arow) * K + kt + ak4];
            As[ak4 + 0][arow] = t4.x;
            As[ak4 + 1][arow] = t4.y;
            As[ak4 + 2][arow] = t4.z;
            As[ak4 + 3][arow] = t4.w;
        } else {
            const AT* ap = &A[(size_t)(m0 + arow) * K + kt + ak4];
            As[ak4 + 0][arow] = __bfloat162float(ap[0]);
            As[ak4 + 1][arow] = __bfloat162float(ap[1]);
            As[ak4 + 2][arow] = __bfloat162float(ap[2]);
            As[ak4 + 3][arow] = __bfloat162float(ap[3]);
        }
        // load B tile 8x128
        {
            float4 t4 = *(const float4*)&Bm[(size_t)(kt + bk) * N + n0 + bn4];
            *(float4*)&Bs[bk][bn4] = t4;
        }
        __syncthreads();
#pragma unroll
        for (int kk = 0; kk < 8; kk++) {
            float4 a0 = *(const float4*)&As[kk][tr * 4];
            float4 a1 = *(const float4*)&As[kk][64 + tr * 4];
            float4 b0 = *(const float4*)&Bs[kk][tc * 4];
            float4 b1 = *(const float4*)&Bs[kk][64 + tc * 4];
            float av[8] = {a0.x, a0.y, a0.z, a0.w, a1.x, a1.y, a1.z, a1.w};
            float bv[8] = {b0.x, b0.y, b0.z, b0.w, b1.x, b1.y, b1.z, b1.w};
#pragma unroll
            for (int i = 0; i < 8; i++)
#pragma unroll
                for (int j = 0; j < 8; j++)
                    acc[i][j] = fmaf(av[i], bv[j], acc[i][j]);
        }
    }

#pragma unroll
    for (int i = 0; i < 8; i++) {
        int r_off = (i < 4) ? (tr * 4 + i) : (64 + tr * 4 + i - 4);
        size_t row = (size_t)(m0 + r_off);
#pragma unroll
        for (int j = 0; j < 8; j++) {
            int c_off = (j < 4) ? (tc * 4 + j) : (64 + tc * 4 + j - 4);
            int col = n0 + c_off;
            float v = acc[i][j];
            if constexpr (EPI >= 1) v += bias[col];
            if constexpr (EPI == 2) v += res[row * (size_t)N + col];
            outp[row * (size_t)N + col] = v;
        }
    }
}

// ---------------- Fused wg GEMM + GEGLU, bf16 output (R x 2048) ----------------
__global__ __launch_bounds__(256) void gemm_geglu(const float* __restrict__ A,
                                                  const float* __restrict__ Wg,
                                                  const float* __restrict__ bg,
                                                  bf16* __restrict__ agout) {
    __shared__ float As[8][128];
    __shared__ float Bs1[8][68];
    __shared__ float Bs2[8][68];
    int m0 = blockIdx.y * 128;
    int n0 = blockIdx.x * 64;     // over 2048 cols
    int tid = threadIdx.x;
    int tc = tid & 15, tr = tid >> 4;

    float acc_a[8][4], acc_g[8][4];
#pragma unroll
    for (int i = 0; i < 8; i++)
#pragma unroll
        for (int j = 0; j < 4; j++) { acc_a[i][j] = 0.f; acc_g[i][j] = 0.f; }

    int arow = tid >> 1, ak4 = (tid & 1) * 4;
    const int K = 512, NW = 4096;

    for (int kt = 0; kt < K; kt += 8) {
        __syncthreads();
        {
            float4 t4 = *(const float4*)&A[(size_t)(m0 + arow) * K + kt + ak4];
            As[ak4 + 0][arow] = t4.x;
            As[ak4 + 1][arow] = t4.y;
            As[ak4 + 2][arow] = t4.z;
            As[ak4 + 3][arow] = t4.w;
        }
        {
            int t = tid & 127;
            int bk = t >> 4, bn4 = (t & 15) * 4;
            int add = (tid < 128) ? 0 : 2048;
            float4 t4 = *(const float4*)&Wg[(size_t)(kt + bk) * NW + add + n0 + bn4];
            if (tid < 128) *(float4*)&Bs1[bk][bn4] = t4;
            else           *(float4*)&Bs2[bk][bn4] = t4;
        }
        __syncthreads();
#pragma unroll
        for (int kk = 0; kk < 8; kk++) {
            float4 a0 = *(const float4*)&As[kk][tr * 4];
            float4 a1 = *(const float4*)&As[kk][64 + tr * 4];
            float4 b1 = *(const float4*)&Bs1[kk][tc * 4];
            float4 b2 = *(const float4*)&Bs2[kk][tc * 4];
            float av[8] = {a0.x, a0.y, a0.z, a0.w, a1.x, a1.y, a1.z, a1.w};
            float bv1[4] = {b1.x, b1.y, b1.z, b1.w};
            float bv2[4] = {b2.x, b2.y, b2.z, b2.w};
#pragma unroll
            for (int i = 0; i < 8; i++)
#pragma unroll
                for (int j = 0; j < 4; j++) {
                    acc_a[i][j] = fmaf(av[i], bv1[j], acc_a[i][j]);
                    acc_g[i][j] = fmaf(av[i], bv2[j], acc_g[i][j]);
                }
        }
    }

#pragma unroll
    for (int i = 0; i < 8; i++) {
        int r_off = (i < 4) ? (tr * 4 + i) : (64 + tr * 4 + i - 4);
        size_t row = (size_t)(m0 + r_off);
#pragma unroll
        for (int j = 0; j < 4; j++) {
            int col = n0 + tc * 4 + j;
            float a = acc_a[i][j] + bg[col];
            float g = acc_g[i][j] + bg[2048 + col];
            float ge = 0.5f * g * (1.0f + erff(g * 0.70710678118654752f));
            agout[row * 2048 + col] = __float2bfloat16(a * ge);
        }
    }
}

// ---------------- Attention: one block per (b,h,s) query ----------------
__global__ __launch_bounds__(256) void attn_kernel(const float* __restrict__ q,
                                                   const float* __restrict__ k,
                                                   const float* __restrict__ v,
                                                   float* __restrict__ o) {
    int s = blockIdx.x, h = blockIdx.y, b = blockIdx.z;
    int tid = threadIdx.x;
    const size_t headbase = (size_t)b * Ss * Cch + (size_t)h * DHh;
    __shared__ float p[1024];
    __shared__ float qs[64];
    __shared__ float red[4];
    __shared__ float mred, sred;
    __shared__ float pr[4][64];

    if (tid < 64) qs[tid] = q[headbase + (size_t)s * Cch + tid];
    __syncthreads();

    float sc[4];
    float mx = -1e30f;
#pragma unroll
    for (int i = 0; i < 4; i++) {
        int t = tid * 4 + i;
        const float* kp = k + headbase + (size_t)t * Cch;
        float d = 0.f;
#pragma unroll 8
        for (int j = 0; j < 64; j++) d = fmaf(qs[j], kp[j], d);
        sc[i] = d * 0.125f;   // 1/sqrt(64)
        mx = fmaxf(mx, sc[i]);
    }
    for (int o2 = 32; o2 > 0; o2 >>= 1) mx = fmaxf(mx, __shfl_down(mx, o2));
    int wid = tid >> 6, lane = tid & 63;
    if (lane == 0) red[wid] = mx;
    __syncthreads();
    if (tid == 0) mred = fmaxf(fmaxf(red[0], red[1]), fmaxf(red[2], red[3]));
    __syncthreads();
    mx = mred;
    float sum = 0.f;
#pragma unroll
    for (int i = 0; i < 4; i++) {
        float e = __expf(sc[i] - mx);
        p[tid * 4 + i] = e;
        sum += e;
    }
    for (int o2 = 32; o2 > 0; o2 >>= 1) sum += __shfl_down(sum, o2);
    if (lane == 0) red[wid] = sum;
    __syncthreads();
    if (tid == 0) sred = red[0] + red[1] + red[2] + red[3];
    __syncthreads();
    float inv = 1.0f / sred;
#pragma unroll
    for (int i = 0; i < 4; i++) p[tid * 4 + i] *= inv;
    __syncthreads();

    int d = tid & 63, tq = tid >> 6;
    float o_acc = 0.f;
    const float* vb = v + headbase + d;
    for (int t = tq * 256; t < tq * 256 + 256; t++)
        o_acc = fmaf(p[t], vb[(size_t)t * Cch], o_acc);
    pr[tq][d] = o_acc;
    __syncthreads();
    if (tq == 0) {
        float r = pr[0][d] + pr[1][d] + pr[2][d] + pr[3][d];
        o[headbase + (size_t)s * Cch + d] = r;
    }
}

// ---------------- final: out(B,C,S) = tmp(B,S,C)^T + x ----------------
__global__ __launch_bounds__(256) void final_out(const float* __restrict__ tmp,
                                                 const float* __restrict__ x,
                                                 float* __restrict__ outp) {
    __shared__ float tile[32][33];
    int b = blockIdx.z, c0 = blockIdx.y * 32, s0 = blockIdx.x * 32;
    int tx = threadIdx.x, ty = threadIdx.y;
#pragma unroll
    for (int i = 0; i < 4; i++) {
        int s = s0 + ty + i * 8;
        tile[ty + i * 8][tx] = tmp[((size_t)b * Ss + s) * Cch + c0 + tx];
    }
    __syncthreads();
#pragma unroll
    for (int i = 0; i < 4; i++) {
        int c = c0 + ty + i * 8;
        size_t idx = ((size_t)b * Cch + c) * Ss + s0 + tx;
        outp[idx] = tile[tx][ty + i * 8] + x[idx];
    }
}

extern "C" void kernel_launch(void* const* d_in, const int* in_sizes, int n_in,
                              void* d_out, int out_size, void* d_ws, size_t ws_size,
                              hipStream_t stream) {
    (void)in_sizes; (void)n_in; (void)out_size; (void)ws_size;
    const float* x      = (const float*)d_in[0];
    const float* gn_w   = (const float*)d_in[1];
    const float* gn_b   = (const float*)d_in[2];
    const float* pin_w  = (const float*)d_in[3];
    const float* pin_b  = (const float*)d_in[4];
    const float* ln1_w  = (const float*)d_in[5];
    const float* ln1_b  = (const float*)d_in[6];
    const float* wq     = (const float*)d_in[7];
    const float* wk     = (const float*)d_in[8];
    const float* wv     = (const float*)d_in[9];
    const float* wo     = (const float*)d_in[10];
    const float* bo     = (const float*)d_in[11];
    const float* ln3_w  = (const float*)d_in[12];
    const float* ln3_b  = (const float*)d_in[13];
    const float* wg     = (const float*)d_in[14];
    const float* bg     = (const float*)d_in[15];
    const float* wd     = (const float*)d_in[16];
    const float* bd     = (const float*)d_in[17];
    const float* pout_w = (const float*)d_in[18];
    const float* pout_b = (const float*)d_in[19];
    float* out = (float*)d_out;

    const size_t SLOT = (size_t)R_TOTAL * Cch;     // 8.39M floats = 33.5 MB
    float* wsA  = (float*)d_ws;
    float* wsB  = wsA + SLOT;
    float* wsC  = wsB + SLOT;
    float* wsD  = wsC + SLOT;
    float* wsE  = wsD + SLOT;
    float* stats = wsE + SLOT;          // 256 floats
    float* pinT  = stats + 256;         // 512*512
    float* poutT = pinT + 512 * 512;    // 512*512
    bf16*  ag    = (bf16*)wsC;          // R x 2048 bf16 (spans slots C+D)

    dim3 tb(32, 8);

    gn_stats<<<128, 256, 0, stream>>>(x, stats);
    transpose512<<<dim3(16, 16), tb, 0, stream>>>(pin_w, pinT);
    transpose512<<<dim3(16, 16), tb, 0, stream>>>(pout_w, poutT);
    gn_apply_t<<<dim3(32, 16, 16), tb, 0, stream>>>(x, stats, gn_w, gn_b, wsA);

    // t = h @ pin_w^T + pin_b   (A: wsA, out: wsB)
    gemm128<float, 1><<<dim3(4, 128), 256, 0, stream>>>(wsA, pinT, pin_b, nullptr, wsB, 512, 512);
    // tn = ln1(t)
    layer_norm_rows<<<16384, 256, 0, stream>>>(wsB, ln1_w, ln1_b, wsA);
    // q, k, v
    gemm128<float, 0><<<dim3(4, 128), 256, 0, stream>>>(wsA, wq, nullptr, nullptr, wsC, 512, 512);
    gemm128<float, 0><<<dim3(4, 128), 256, 0, stream>>>(wsA, wk, nullptr, nullptr, wsD, 512, 512);
    gemm128<float, 0><<<dim3(4, 128), 256, 0, stream>>>(wsA, wv, nullptr, nullptr, wsE, 512, 512);
    // attention -> wsA
    attn_kernel<<<dim3(1024, 8, 16), 256, 0, stream>>>(wsC, wsD, wsE, wsA);
    // t = attn @ wo + bo + t   (in-place residual on wsB)
    gemm128<float, 2><<<dim3(4, 128), 256, 0, stream>>>(wsA, wo, bo, wsB, wsB, 512, 512);
    // tn3 = ln3(t)
    layer_norm_rows<<<16384, 256, 0, stream>>>(wsB, ln3_w, ln3_b, wsA);
    // ag = a * gelu(g), bf16  (wg fused)
    gemm_geglu<<<dim3(32, 128), 256, 0, stream>>>(wsA, wg, bg, ag);
    // t = ag @ wd + bd + t  (in-place on wsB)
    gemm128<bf16, 2><<<dim3(4, 128), 256, 0, stream>>>(ag, wd, bd, wsB, wsB, 2048, 512);
    // tmp = t @ pout_w^T + pout_b  -> wsA
    gemm128<float, 1><<<dim3(4, 128), 256, 0, stream>>>(wsB, poutT, pout_b, nullptr, wsA, 512, 512);
    // out = tmp^T + x
    final_out<<<dim3(32, 16, 16), tb, 0, stream>>>(wsA, x, out);
}

// Round 6
// 2511.872 us; speedup vs baseline: 2.8517x; 2.8517x over previous
//
#include <hip/hip_runtime.h>
#include <hip/hip_bf16.h>
#include <math.h>
#include <type_traits>

typedef __hip_bfloat16 bf16;

#define Bb 16
#define Cch 512
#define Ss 1024          // H*W = 32*32
#define NHh 8
#define DHh 64
#define CPG 64           // channels per group (512/8)
#define EPSV 1e-5f
#define R_TOTAL (Bb*Ss)  // 16384

// ---------------- GroupNorm: per-(b,g) stats ----------------
__global__ __launch_bounds__(256) void gn_stats(const float* __restrict__ x,
                                                float* __restrict__ stats) {
    int bg = blockIdx.x;               // 0..127  (b*8+g)
    int b = bg >> 3, g = bg & 7;
    const float* base = x + ((size_t)b * Cch + (size_t)g * CPG) * Ss;
    float s = 0.f, ss = 0.f;
    for (int i = threadIdx.x; i < CPG * Ss; i += 256) {
        float v = base[i];
        s += v; ss += v * v;
    }
    for (int o = 32; o > 0; o >>= 1) { s += __shfl_down(s, o); ss += __shfl_down(ss, o); }
    __shared__ float red[2][4];
    int wid = threadIdx.x >> 6, lane = threadIdx.x & 63;
    if (lane == 0) { red[0][wid] = s; red[1][wid] = ss; }
    __syncthreads();
    if (threadIdx.x == 0) {
        float S1 = red[0][0] + red[0][1] + red[0][2] + red[0][3];
        float S2 = red[1][0] + red[1][1] + red[1][2] + red[1][3];
        const float inv_n = 1.0f / (CPG * Ss);
        float mu = S1 * inv_n;
        float var = S2 * inv_n - mu * mu;
        stats[bg * 2]     = mu;
        stats[bg * 2 + 1] = rsqrtf(var + EPSV);
    }
}

// ---------------- GroupNorm apply + transpose (B,C,S)->(B,S,C) ----------------
__global__ __launch_bounds__(256) void gn_apply_t(const float* __restrict__ x,
                                                  const float* __restrict__ stats,
                                                  const float* __restrict__ gw,
                                                  const float* __restrict__ gb,
                                                  float* __restrict__ ht) {
    __shared__ float tile[32][33];
    int b  = blockIdx.z;
    int c0 = blockIdx.y * 32;
    int s0 = blockIdx.x * 32;
    int tx = threadIdx.x, ty = threadIdx.y;
#pragma unroll
    for (int i = 0; i < 4; i++) {
        int c = c0 + ty + i * 8;
        int g = c >> 6;
        float mu = stats[(b * 8 + g) * 2];
        float rs = stats[(b * 8 + g) * 2 + 1];
        float v = x[((size_t)b * Cch + c) * Ss + s0 + tx];
        tile[ty + i * 8][tx] = (v - mu) * rs * gw[c] + gb[c];
    }
    __syncthreads();
#pragma unroll
    for (int i = 0; i < 4; i++) {
        int s = s0 + ty + i * 8;
        ht[((size_t)b * Ss + s) * Cch + c0 + tx] = tile[tx][ty + i * 8];
    }
}

// ---------------- 512x512 transpose (for pin_w, pout_w) ----------------
__global__ __launch_bounds__(256) void transpose512(const float* __restrict__ in,
                                                    float* __restrict__ outp) {
    __shared__ float tile[32][33];
    int c0 = blockIdx.x * 32, r0 = blockIdx.y * 32;
    int tx = threadIdx.x, ty = threadIdx.y;
#pragma unroll
    for (int i = 0; i < 4; i++)
        tile[ty + i * 8][tx] = in[(size_t)(r0 + ty + i * 8) * 512 + c0 + tx];
    __syncthreads();
#pragma unroll
    for (int i = 0; i < 4; i++)
        outp[(size_t)(c0 + ty + i * 8) * 512 + r0 + tx] = tile[tx][ty + i * 8];
}

// ---------------- LayerNorm over rows of (R,512) ----------------
__global__ __launch_bounds__(256) void layer_norm_rows(const float* __restrict__ in,
                                                       const float* __restrict__ w,
                                                       const float* __restrict__ bb,
                                                       float* __restrict__ outp) {
    int row = blockIdx.x;
    const float* p = in + (size_t)row * Cch;
    float v0 = p[threadIdx.x], v1 = p[threadIdx.x + 256];
    float s = v0 + v1, ss = v0 * v0 + v1 * v1;
    for (int o = 32; o > 0; o >>= 1) { s += __shfl_down(s, o); ss += __shfl_down(ss, o); }
    __shared__ float red[2][4];
    __shared__ float mu_s, rs_s;
    int wid = threadIdx.x >> 6, lane = threadIdx.x & 63;
    if (lane == 0) { red[0][wid] = s; red[1][wid] = ss; }
    __syncthreads();
    if (threadIdx.x == 0) {
        float S1 = red[0][0] + red[0][1] + red[0][2] + red[0][3];
        float S2 = red[1][0] + red[1][1] + red[1][2] + red[1][3];
        float mu = S1 * (1.0f / Cch);
        float var = S2 * (1.0f / Cch) - mu * mu;
        mu_s = mu; rs_s = rsqrtf(var + EPSV);
    }
    __syncthreads();
    float mu = mu_s, rs = rs_s;
    outp[(size_t)row * Cch + threadIdx.x]       = (v0 - mu) * rs * w[threadIdx.x] + bb[threadIdx.x];
    outp[(size_t)row * Cch + threadIdx.x + 256] = (v1 - mu) * rs * w[threadIdx.x + 256] + bb[threadIdx.x + 256];
}

// ---------------- Generic SGEMM: out(RxN) = A(RxK) @ B(KxN) [+bias][+res] ----------------
// EPI: 0 = none, 1 = +bias, 2 = +bias +res (res may alias out; in-place safe)
template<typename AT, int EPI>
__global__ __launch_bounds__(256) void gemm128(const AT* __restrict__ A,
                                               const float* __restrict__ Bm,
                                               const float* __restrict__ bias,
                                               const float* __restrict__ res,
                                               float* __restrict__ outp,
                                               int K, int N) {
    __shared__ float As[8][128];
    __shared__ float Bs[8][132];
    int m0 = blockIdx.y * 128;
    int n0 = blockIdx.x * 128;
    int tid = threadIdx.x;
    int tc = tid & 15, tr = tid >> 4;

    float acc[8][8];
#pragma unroll
    for (int i = 0; i < 8; i++)
#pragma unroll
        for (int j = 0; j < 8; j++) acc[i][j] = 0.f;

    int arow = tid >> 1, ak4 = (tid & 1) * 4;
    int bk = tid >> 5, bn4 = (tid & 31) * 4;

    for (int kt = 0; kt < K; kt += 8) {
        __syncthreads();
        // load A tile 128x8 (transposed into [k][m])
        if constexpr (std::is_same<AT, float>::value) {
            float4 t4 = *(const float4*)&A[(size_t)(m0 + arow) * K + kt + ak4];
            As[ak4 + 0][arow] = t4.x;
            As[ak4 + 1][arow] = t4.y;
            As[ak4 + 2][arow] = t4.z;
            As[ak4 + 3][arow] = t4.w;
        } else {
            const AT* ap = &A[(size_t)(m0 + arow) * K + kt + ak4];
            As[ak4 + 0][arow] = __bfloat162float(ap[0]);
            As[ak4 + 1][arow] = __bfloat162float(ap[1]);
            As[ak4 + 2][arow] = __bfloat162float(ap[2]);
            As[ak4 + 3][arow] = __bfloat162float(ap[3]);
        }
        // load B tile 8x128
        {
            float4 t4 = *(const float4*)&Bm[(size_t)(kt + bk) * N + n0 + bn4];
            *(float4*)&Bs[bk][bn4] = t4;
        }
        __syncthreads();
#pragma unroll
        for (int kk = 0; kk < 8; kk++) {
            float4 a0 = *(const float4*)&As[kk][tr * 4];
            float4 a1 = *(const float4*)&As[kk][64 + tr * 4];
            float4 b0 = *(const float4*)&Bs[kk][tc * 4];
            float4 b1 = *(const float4*)&Bs[kk][64 + tc * 4];
            float av[8] = {a0.x, a0.y, a0.z, a0.w, a1.x, a1.y, a1.z, a1.w};
            float bv[8] = {b0.x, b0.y, b0.z, b0.w, b1.x, b1.y, b1.z, b1.w};
#pragma unroll
            for (int i = 0; i < 8; i++)
#pragma unroll
                for (int j = 0; j < 8; j++)
                    acc[i][j] = fmaf(av[i], bv[j], acc[i][j]);
        }
    }

#pragma unroll
    for (int i = 0; i < 8; i++) {
        int r_off = (i < 4) ? (tr * 4 + i) : (64 + tr * 4 + i - 4);
        size_t row = (size_t)(m0 + r_off);
#pragma unroll
        for (int j = 0; j < 8; j++) {
            int c_off = (j < 4) ? (tc * 4 + j) : (64 + tc * 4 + j - 4);
            int col = n0 + c_off;
            float v = acc[i][j];
            if constexpr (EPI >= 1) v += bias[col];
            if constexpr (EPI == 2) v += res[row * (size_t)N + col];
            outp[row * (size_t)N + col] = v;
        }
    }
}

// ---------------- Fused wg GEMM + GEGLU, bf16 output (R x 2048) ----------------
__global__ __launch_bounds__(256) void gemm_geglu(const float* __restrict__ A,
                                                  const float* __restrict__ Wg,
                                                  const float* __restrict__ bg,
                                                  bf16* __restrict__ agout) {
    __shared__ float As[8][128];
    __shared__ float Bs1[8][68];
    __shared__ float Bs2[8][68];
    int m0 = blockIdx.y * 128;
    int n0 = blockIdx.x * 64;     // over 2048 cols
    int tid = threadIdx.x;
    int tc = tid & 15, tr = tid >> 4;

    float acc_a[8][4], acc_g[8][4];
#pragma unroll
    for (int i = 0; i < 8; i++)
#pragma unroll
        for (int j = 0; j < 4; j++) { acc_a[i][j] = 0.f; acc_g[i][j] = 0.f; }

    int arow = tid >> 1, ak4 = (tid & 1) * 4;
    const int K = 512, NW = 4096;

    for (int kt = 0; kt < K; kt += 8) {
        __syncthreads();
        {
            float4 t4 = *(const float4*)&A[(size_t)(m0 + arow) * K + kt + ak4];
            As[ak4 + 0][arow] = t4.x;
            As[ak4 + 1][arow] = t4.y;
            As[ak4 + 2][arow] = t4.z;
            As[ak4 + 3][arow] = t4.w;
        }
        {
            int t = tid & 127;
            int bk = t >> 4, bn4 = (t & 15) * 4;
            int add = (tid < 128) ? 0 : 2048;
            float4 t4 = *(const float4*)&Wg[(size_t)(kt + bk) * NW + add + n0 + bn4];
            if (tid < 128) *(float4*)&Bs1[bk][bn4] = t4;
            else           *(float4*)&Bs2[bk][bn4] = t4;
        }
        __syncthreads();
#pragma unroll
        for (int kk = 0; kk < 8; kk++) {
            float4 a0 = *(const float4*)&As[kk][tr * 4];
            float4 a1 = *(const float4*)&As[kk][64 + tr * 4];
            float4 b1 = *(const float4*)&Bs1[kk][tc * 4];
            float4 b2 = *(const float4*)&Bs2[kk][tc * 4];
            float av[8] = {a0.x, a0.y, a0.z, a0.w, a1.x, a1.y, a1.z, a1.w};
            float bv1[4] = {b1.x, b1.y, b1.z, b1.w};
            float bv2[4] = {b2.x, b2.y, b2.z, b2.w};
#pragma unroll
            for (int i = 0; i < 8; i++)
#pragma unroll
                for (int j = 0; j < 4; j++) {
                    acc_a[i][j] = fmaf(av[i], bv1[j], acc_a[i][j]);
                    acc_g[i][j] = fmaf(av[i], bv2[j], acc_g[i][j]);
                }
        }
    }

#pragma unroll
    for (int i = 0; i < 8; i++) {
        int r_off = (i < 4) ? (tr * 4 + i) : (64 + tr * 4 + i - 4);
        size_t row = (size_t)(m0 + r_off);
#pragma unroll
        for (int j = 0; j < 4; j++) {
            int col = n0 + tc * 4 + j;
            float a = acc_a[i][j] + bg[col];
            float g = acc_g[i][j] + bg[2048 + col];
            float ge = 0.5f * g * (1.0f + erff(g * 0.70710678118654752f));
            agout[row * 2048 + col] = __float2bfloat16(a * ge);
        }
    }
}

// ---------------- Flash attention (fp32, LDS-tiled, online softmax) ----------------
// Grid: (S/64, NH, B), block 256.  Per block: 64 queries, loop KV in 64-tiles.
// Thread (g = tid>>4, c = tid&15): QK phase owns q rows 4g..4g+4, kv cols {c+16j};
// PV phase owns q rows 4g..4g+4, d cols 4c..4c+4.
// LDS rows padded to 68 floats: keeps 16B alignment; all hot reads <=2-way bank alias.
__global__ __launch_bounds__(256) void flash_attn(const float* __restrict__ q,
                                                  const float* __restrict__ k,
                                                  const float* __restrict__ v,
                                                  float* __restrict__ o) {
    __shared__ float Qs[64][68];
    __shared__ float Ks[64][68];
    __shared__ float Vs[64][68];
    __shared__ float Ps[64][68];
    const int tid = threadIdx.x;
    const int h = blockIdx.y, b = blockIdx.z;
    const int q0 = blockIdx.x * 64;
    const size_t hb = (size_t)b * Ss * Cch + (size_t)h * DHh;

    const int g  = tid >> 4;       // 0..15
    const int c  = tid & 15;       // 0..15
    const int qg = g * 4;

    // load Q tile (64 x 64), coalesced
    {
        int r = tid >> 2, c4 = (tid & 3) * 16;
        const float* src = q + hb + (size_t)(q0 + r) * Cch + c4;
#pragma unroll
        for (int u = 0; u < 4; u++)
            *(float4*)&Qs[r][c4 + u * 4] = *(const float4*)&src[u * 4];
    }

    float m_[4], l_[4], o_[4][4];
#pragma unroll
    for (int i = 0; i < 4; i++) {
        m_[i] = -3.0e38f; l_[i] = 0.f;
#pragma unroll
        for (int j = 0; j < 4; j++) o_[i][j] = 0.f;
    }

    for (int t0 = 0; t0 < Ss; t0 += 64) {
        __syncthreads();   // prev PV done; Ks/Vs/Ps reusable
        {
            int r = tid >> 2, c4 = (tid & 3) * 16;
            const float* ksrc = k + hb + (size_t)(t0 + r) * Cch + c4;
            const float* vsrc = v + hb + (size_t)(t0 + r) * Cch + c4;
#pragma unroll
            for (int u = 0; u < 4; u++) {
                *(float4*)&Ks[r][c4 + u * 4] = *(const float4*)&ksrc[u * 4];
                *(float4*)&Vs[r][c4 + u * 4] = *(const float4*)&vsrc[u * 4];
            }
        }
        __syncthreads();

        // scores: s_[i][j] = Q[qg+i] . K[c+16j]
        float s_[4][4];
#pragma unroll
        for (int i = 0; i < 4; i++)
#pragma unroll
            for (int j = 0; j < 4; j++) s_[i][j] = 0.f;
        for (int kk = 0; kk < 64; kk += 4) {
            float4 qv[4], kv[4];
#pragma unroll
            for (int i = 0; i < 4; i++) qv[i] = *(const float4*)&Qs[qg + i][kk];
#pragma unroll
            for (int j = 0; j < 4; j++) kv[j] = *(const float4*)&Ks[c + 16 * j][kk];
#pragma unroll
            for (int i = 0; i < 4; i++)
#pragma unroll
                for (int j = 0; j < 4; j++) {
                    s_[i][j] = fmaf(qv[i].x, kv[j].x, s_[i][j]);
                    s_[i][j] = fmaf(qv[i].y, kv[j].y, s_[i][j]);
                    s_[i][j] = fmaf(qv[i].z, kv[j].z, s_[i][j]);
                    s_[i][j] = fmaf(qv[i].w, kv[j].w, s_[i][j]);
                }
        }

        // online softmax update (per q row; reduce across the 16 c-lanes)
#pragma unroll
        for (int i = 0; i < 4; i++) {
#pragma unroll
            for (int j = 0; j < 4; j++) s_[i][j] *= 0.125f;   // 1/sqrt(64)
            float tm = fmaxf(fmaxf(s_[i][0], s_[i][1]), fmaxf(s_[i][2], s_[i][3]));
            tm = fmaxf(tm, __shfl_xor(tm, 1));
            tm = fmaxf(tm, __shfl_xor(tm, 2));
            tm = fmaxf(tm, __shfl_xor(tm, 4));
            tm = fmaxf(tm, __shfl_xor(tm, 8));
            float nm = fmaxf(m_[i], tm);
            float sc = __expf(m_[i] - nm);
            m_[i] = nm;
            float rs = 0.f;
#pragma unroll
            for (int j = 0; j < 4; j++) {
                float p = __expf(s_[i][j] - nm);
                Ps[qg + i][c + 16 * j] = p;
                rs += p;
            }
            rs += __shfl_xor(rs, 1);
            rs += __shfl_xor(rs, 2);
            rs += __shfl_xor(rs, 4);
            rs += __shfl_xor(rs, 8);
            l_[i] = l_[i] * sc + rs;
#pragma unroll
            for (int j = 0; j < 4; j++) o_[i][j] *= sc;
        }
        __syncthreads();   // Ps ready

        // PV: o_[i][j] += sum_t Ps[qg+i][t] * Vs[t][4c+j]
        for (int tt = 0; tt < 64; tt += 4) {
            float4 vv[4];
#pragma unroll
            for (int u = 0; u < 4; u++) vv[u] = *(const float4*)&Vs[tt + u][c * 4];
#pragma unroll
            for (int i = 0; i < 4; i++) {
                float4 p4 = *(const float4*)&Ps[qg + i][tt];
                o_[i][0] = fmaf(p4.x, vv[0].x, o_[i][0]);
                o_[i][1] = fmaf(p4.x, vv[0].y, o_[i][1]);
                o_[i][2] = fmaf(p4.x, vv[0].z, o_[i][2]);
                o_[i][3] = fmaf(p4.x, vv[0].w, o_[i][3]);
                o_[i][0] = fmaf(p4.y, vv[1].x, o_[i][0]);
                o_[i][1] = fmaf(p4.y, vv[1].y, o_[i][1]);
                o_[i][2] = fmaf(p4.y, vv[1].z, o_[i][2]);
                o_[i][3] = fmaf(p4.y, vv[1].w, o_[i][3]);
                o_[i][0] = fmaf(p4.z, vv[2].x, o_[i][0]);
                o_[i][1] = fmaf(p4.z, vv[2].y, o_[i][1]);
                o_[i][2] = fmaf(p4.z, vv[2].z, o_[i][2]);
                o_[i][3] = fmaf(p4.z, vv[2].w, o_[i][3]);
                o_[i][0] = fmaf(p4.w, vv[3].x, o_[i][0]);
                o_[i][1] = fmaf(p4.w, vv[3].y, o_[i][1]);
                o_[i][2] = fmaf(p4.w, vv[3].z, o_[i][2]);
                o_[i][3] = fmaf(p4.w, vv[3].w, o_[i][3]);
            }
        }
    }

    // finalize + store (coalesced float4)
#pragma unroll
    for (int i = 0; i < 4; i++) {
        float inv = 1.0f / l_[i];
        float4 r4 = { o_[i][0] * inv, o_[i][1] * inv, o_[i][2] * inv, o_[i][3] * inv };
        *(float4*)&o[hb + (size_t)(q0 + qg + i) * Cch + c * 4] = r4;
    }
}

// ---------------- final: out(B,C,S) = tmp(B,S,C)^T + x ----------------
__global__ __launch_bounds__(256) void final_out(const float* __restrict__ tmp,
                                                 const float* __restrict__ x,
                                                 float* __restrict__ outp) {
    __shared__ float tile[32][33];
    int b = blockIdx.z, c0 = blockIdx.y * 32, s0 = blockIdx.x * 32;
    int tx = threadIdx.x, ty = threadIdx.y;
#pragma unroll
    for (int i = 0; i < 4; i++) {
        int s = s0 + ty + i * 8;
        tile[ty + i * 8][tx] = tmp[((size_t)b * Ss + s) * Cch + c0 + tx];
    }
    __syncthreads();
#pragma unroll
    for (int i = 0; i < 4; i++) {
        int c = c0 + ty + i * 8;
        size_t idx = ((size_t)b * Cch + c) * Ss + s0 + tx;
        outp[idx] = tile[tx][ty + i * 8] + x[idx];
    }
}

extern "C" void kernel_launch(void* const* d_in, const int* in_sizes, int n_in,
                              void* d_out, int out_size, void* d_ws, size_t ws_size,
                              hipStream_t stream) {
    (void)in_sizes; (void)n_in; (void)out_size; (void)ws_size;
    const float* x      = (const float*)d_in[0];
    const float* gn_w   = (const float*)d_in[1];
    const float* gn_b   = (const float*)d_in[2];
    const float* pin_w  = (const float*)d_in[3];
    const float* pin_b  = (const float*)d_in[4];
    const float* ln1_w  = (const float*)d_in[5];
    const float* ln1_b  = (const float*)d_in[6];
    const float* wq     = (const float*)d_in[7];
    const float* wk     = (const float*)d_in[8];
    const float* wv     = (const float*)d_in[9];
    const float* wo     = (const float*)d_in[10];
    const float* bo     = (const float*)d_in[11];
    const float* ln3_w  = (const float*)d_in[12];
    const float* ln3_b  = (const float*)d_in[13];
    const float* wg     = (const float*)d_in[14];
    const float* bg     = (const float*)d_in[15];
    const float* wd     = (const float*)d_in[16];
    const float* bd     = (const float*)d_in[17];
    const float* pout_w = (const float*)d_in[18];
    const float* pout_b = (const float*)d_in[19];
    float* out = (float*)d_out;

    const size_t SLOT = (size_t)R_TOTAL * Cch;     // 8.39M floats = 33.5 MB
    float* wsA  = (float*)d_ws;
    float* wsB  = wsA + SLOT;
    float* wsC  = wsB + SLOT;
    float* wsD  = wsC + SLOT;
    float* wsE  = wsD + SLOT;
    float* stats = wsE + SLOT;          // 256 floats
    float* pinT  = stats + 256;         // 512*512
    float* poutT = pinT + 512 * 512;    // 512*512
    bf16*  ag    = (bf16*)wsC;          // R x 2048 bf16 (spans slots C+D)

    dim3 tb(32, 8);

    gn_stats<<<128, 256, 0, stream>>>(x, stats);
    transpose512<<<dim3(16, 16), tb, 0, stream>>>(pin_w, pinT);
    transpose512<<<dim3(16, 16), tb, 0, stream>>>(pout_w, poutT);
    gn_apply_t<<<dim3(32, 16, 16), tb, 0, stream>>>(x, stats, gn_w, gn_b, wsA);

    // t = h @ pin_w^T + pin_b   (A: wsA, out: wsB)
    gemm128<float, 1><<<dim3(4, 128), 256, 0, stream>>>(wsA, pinT, pin_b, nullptr, wsB, 512, 512);
    // tn = ln1(t)
    layer_norm_rows<<<16384, 256, 0, stream>>>(wsB, ln1_w, ln1_b, wsA);
    // q, k, v
    gemm128<float, 0><<<dim3(4, 128), 256, 0, stream>>>(wsA, wq, nullptr, nullptr, wsC, 512, 512);
    gemm128<float, 0><<<dim3(4, 128), 256, 0, stream>>>(wsA, wk, nullptr, nullptr, wsD, 512, 512);
    gemm128<float, 0><<<dim3(4, 128), 256, 0, stream>>>(wsA, wv, nullptr, nullptr, wsE, 512, 512);
    // flash attention -> wsA
    flash_attn<<<dim3(16, 8, 16), 256, 0, stream>>>(wsC, wsD, wsE, wsA);
    // t = attn @ wo + bo + t   (in-place residual on wsB)
    gemm128<float, 2><<<dim3(4, 128), 256, 0, stream>>>(wsA, wo, bo, wsB, wsB, 512, 512);
    // tn3 = ln3(t)
    layer_norm_rows<<<16384, 256, 0, stream>>>(wsB, ln3_w, ln3_b, wsA);
    // ag = a * gelu(g), bf16  (wg fused)
    gemm_geglu<<<dim3(32, 128), 256, 0, stream>>>(wsA, wg, bg, ag);
    // t = ag @ wd + bd + t  (in-place on wsB)
    gemm128<bf16, 2><<<dim3(4, 128), 256, 0, stream>>>(ag, wd, bd, wsB, wsB, 2048, 512);
    // tmp = t @ pout_w^T + pout_b  -> wsA
    gemm128<float, 1><<<dim3(4, 128), 256, 0, stream>>>(wsB, poutT, pout_b, nullptr, wsA, 512, 512);
    // out = tmp^T + x
    final_out<<<dim3(32, 16, 16), tb, 0, stream>>>(wsA, x, out);
}

// Round 9
// 1000.585 us; speedup vs baseline: 7.1589x; 2.5104x over previous
//
#include <hip/hip_runtime.h>
#include <hip/hip_bf16.h>
#include <math.h>

typedef unsigned short u16;
typedef __attribute__((ext_vector_type(8))) short bf16x8;
typedef __attribute__((ext_vector_type(4))) float f32x4;

#define Bb 16
#define Cch 512
#define Ss 1024
#define NHh 8
#define DHh 64
#define CPG 64
#define EPSV 1e-5f
#define R_TOTAL (Bb*Ss)   // 16384

__device__ inline u16 f2bf(float f) {
    unsigned int u = __float_as_uint(f);
    unsigned int r = (u + 0x7fffu + ((u >> 16) & 1u)) >> 16;
    return (u16)r;
}
__device__ inline void bf8f(const u16* s, float* d) {
    int4 u = *(const int4*)s;
    d[0] = __uint_as_float(((unsigned)u.x) << 16); d[1] = __uint_as_float(((unsigned)u.x) & 0xffff0000u);
    d[2] = __uint_as_float(((unsigned)u.y) << 16); d[3] = __uint_as_float(((unsigned)u.y) & 0xffff0000u);
    d[4] = __uint_as_float(((unsigned)u.z) << 16); d[5] = __uint_as_float(((unsigned)u.z) & 0xffff0000u);
    d[6] = __uint_as_float(((unsigned)u.w) << 16); d[7] = __uint_as_float(((unsigned)u.w) & 0xffff0000u);
}

// ---------------- GroupNorm stats ----------------
__global__ __launch_bounds__(256) void gn_stats(const float* __restrict__ x,
                                                float* __restrict__ stats) {
    int bg = blockIdx.x;
    int b = bg >> 3, g = bg & 7;
    const float* base = x + ((size_t)b * Cch + (size_t)g * CPG) * Ss;
    float s = 0.f, ss = 0.f;
    for (int i = threadIdx.x; i < CPG * Ss; i += 256) {
        float v = base[i];
        s += v; ss += v * v;
    }
    for (int o = 32; o > 0; o >>= 1) { s += __shfl_down(s, o); ss += __shfl_down(ss, o); }
    __shared__ float red[2][4];
    int wid = threadIdx.x >> 6, lane = threadIdx.x & 63;
    if (lane == 0) { red[0][wid] = s; red[1][wid] = ss; }
    __syncthreads();
    if (threadIdx.x == 0) {
        float S1 = red[0][0] + red[0][1] + red[0][2] + red[0][3];
        float S2 = red[1][0] + red[1][1] + red[1][2] + red[1][3];
        const float inv_n = 1.0f / (CPG * Ss);
        float mu = S1 * inv_n;
        float var = S2 * inv_n - mu * mu;
        stats[bg * 2]     = mu;
        stats[bg * 2 + 1] = rsqrtf(var + EPSV);
    }
}

// ---------------- GroupNorm apply + transpose -> bf16 (B,S,C) ----------------
__global__ __launch_bounds__(256) void gn_apply_t_bf(const float* __restrict__ x,
                                                     const float* __restrict__ stats,
                                                     const float* __restrict__ gw,
                                                     const float* __restrict__ gb,
                                                     u16* __restrict__ ht) {
    __shared__ float tile[32][33];
    int b  = blockIdx.z;
    int c0 = blockIdx.y * 32;
    int s0 = blockIdx.x * 32;
    int tx = threadIdx.x, ty = threadIdx.y;
#pragma unroll
    for (int i = 0; i < 4; i++) {
        int c = c0 + ty + i * 8;
        int g = c >> 6;
        float mu = stats[(b * 8 + g) * 2];
        float rs = stats[(b * 8 + g) * 2 + 1];
        float v = x[((size_t)b * Cch + c) * Ss + s0 + tx];
        tile[ty + i * 8][tx] = (v - mu) * rs * gw[c] + gb[c];
    }
    __syncthreads();
#pragma unroll
    for (int i = 0; i < 4; i++) {
        int s = s0 + ty + i * 8;
        ht[((size_t)b * Ss + s) * Cch + c0 + tx] = f2bf(tile[tx][ty + i * 8]);
    }
}

// ---------------- fp32 -> bf16 straight convert ----------------
__global__ __launch_bounds__(256) void conv_bf16(const float* __restrict__ in,
                                                 u16* __restrict__ outp, int n) {
    for (int i = blockIdx.x * 256 + threadIdx.x; i < n; i += gridDim.x * 256)
        outp[i] = f2bf(in[i]);
}

// ---------------- transpose + convert: in (R x C) fp32 -> out (C x R) bf16 ----------------
__global__ __launch_bounds__(256) void convT_bf16(const float* __restrict__ in,
                                                  u16* __restrict__ outp, int R, int C) {
    __shared__ float tile[32][33];
    int c0 = blockIdx.x * 32, r0 = blockIdx.y * 32;
    int tx = threadIdx.x, ty = threadIdx.y;
#pragma unroll
    for (int i = 0; i < 4; i++)
        tile[ty + i * 8][tx] = in[(size_t)(r0 + ty + i * 8) * C + c0 + tx];
    __syncthreads();
#pragma unroll
    for (int i = 0; i < 4; i++)
        outp[(size_t)(c0 + ty + i * 8) * R + r0 + tx] = f2bf(tile[tx][ty + i * 8]);
}

// ---------------- LayerNorm rows (fp32 in, bf16 out) ----------------
__global__ __launch_bounds__(256) void layer_norm_rows_bf(const float* __restrict__ in,
                                                          const float* __restrict__ w,
                                                          const float* __restrict__ bb,
                                                          u16* __restrict__ outp) {
    int row = blockIdx.x;
    const float* p = in + (size_t)row * Cch;
    float v0 = p[threadIdx.x], v1 = p[threadIdx.x + 256];
    float s = v0 + v1, ss = v0 * v0 + v1 * v1;
    for (int o = 32; o > 0; o >>= 1) { s += __shfl_down(s, o); ss += __shfl_down(ss, o); }
    __shared__ float red[2][4];
    __shared__ float mu_s, rs_s;
    int wid = threadIdx.x >> 6, lane = threadIdx.x & 63;
    if (lane == 0) { red[0][wid] = s; red[1][wid] = ss; }
    __syncthreads();
    if (threadIdx.x == 0) {
        float S1 = red[0][0] + red[0][1] + red[0][2] + red[0][3];
        float S2 = red[1][0] + red[1][1] + red[1][2] + red[1][3];
        float mu = S1 * (1.0f / Cch);
        float var = S2 * (1.0f / Cch) - mu * mu;
        mu_s = mu; rs_s = rsqrtf(var + EPSV);
    }
    __syncthreads();
    float mu = mu_s, rs = rs_s;
    outp[(size_t)row * Cch + threadIdx.x]       = f2bf((v0 - mu) * rs * w[threadIdx.x] + bb[threadIdx.x]);
    outp[(size_t)row * Cch + threadIdx.x + 256] = f2bf((v1 - mu) * rs * w[threadIdx.x + 256] + bb[threadIdx.x + 256]);
}

// ---------------- MFMA GEMM: out(MxN) = A(MxK bf16) @ Bt(NxK bf16)^T ----------------
// 128x128 tile, BK=32, 256 thr = 4 waves (2x2), per-wave 64x64 = 4x4 16x16 frags.
// EPI: 0 = store bf16 (no bias); 1 = fp32 +bias; 2 = fp32 +bias+res(inplace);
//      3 = EPI2 + bf16 copy to outb.
template<int EPI>
__global__ __launch_bounds__(256) void mfma_gemm(const u16* __restrict__ A,
                                                 const u16* __restrict__ Bt,
                                                 const float* __restrict__ bias,
                                                 float* __restrict__ fout,
                                                 u16* __restrict__ outb,
                                                 int K, int N) {
    __shared__ short As[128 * 32];
    __shared__ short Bs[128 * 32];
    int tid = threadIdx.x;
    int m0 = blockIdx.y * 128, n0 = blockIdx.x * 128;
    int wave = tid >> 6, lane = tid & 63;
    int wr = wave >> 1, wc = wave & 1;
    int l15 = lane & 15, l4 = lane >> 4;

    f32x4 zero4 = {0.f, 0.f, 0.f, 0.f};
    f32x4 acc[4][4];
#pragma unroll
    for (int i = 0; i < 4; i++)
#pragma unroll
        for (int j = 0; j < 4; j++) acc[i][j] = zero4;

    int srow = tid >> 1;
    int se   = (tid & 1) * 16;   // element offset within 32-elem row (0 or 16)

    int4 ra0, ra1, rb0, rb1;
    {
        const u16* pa = A  + (size_t)(m0 + srow) * K + se;
        ra0 = *(const int4*)pa; ra1 = *(const int4*)(pa + 8);
        const u16* pb = Bt + (size_t)(n0 + srow) * K + se;
        rb0 = *(const int4*)pb; rb1 = *(const int4*)(pb + 8);
    }
    for (int kt = 0; kt < K; kt += 32) {
        __syncthreads();
        *(int4*)&As[srow * 32 + se]     = ra0;
        *(int4*)&As[srow * 32 + se + 8] = ra1;
        *(int4*)&Bs[srow * 32 + se]     = rb0;
        *(int4*)&Bs[srow * 32 + se + 8] = rb1;
        __syncthreads();
        int kn = kt + 32;
        if (kn < K) {
            const u16* pa = A  + (size_t)(m0 + srow) * K + kn + se;
            ra0 = *(const int4*)pa; ra1 = *(const int4*)(pa + 8);
            const u16* pb = Bt + (size_t)(n0 + srow) * K + kn + se;
            rb0 = *(const int4*)pb; rb1 = *(const int4*)(pb + 8);
        }
        bf16x8 af[4], bfr[4];
#pragma unroll
        for (int mi = 0; mi < 4; mi++)
            af[mi] = *(const bf16x8*)&As[(wr * 64 + mi * 16 + l15) * 32 + l4 * 8];
#pragma unroll
        for (int nj = 0; nj < 4; nj++)
            bfr[nj] = *(const bf16x8*)&Bs[(wc * 64 + nj * 16 + l15) * 32 + l4 * 8];
#pragma unroll
        for (int mi = 0; mi < 4; mi++)
#pragma unroll
            for (int nj = 0; nj < 4; nj++)
                acc[mi][nj] = __builtin_amdgcn_mfma_f32_16x16x32_bf16(af[mi], bfr[nj], acc[mi][nj], 0, 0, 0);
    }

#pragma unroll
    for (int mi = 0; mi < 4; mi++)
#pragma unroll
        for (int nj = 0; nj < 4; nj++)
#pragma unroll
            for (int r = 0; r < 4; r++) {
                int row = m0 + wr * 64 + mi * 16 + l4 * 4 + r;
                int col = n0 + wc * 64 + nj * 16 + l15;
                float v = acc[mi][nj][r];
                if constexpr (EPI == 0) {
                    outb[(size_t)row * N + col] = f2bf(v);
                } else {
                    v += bias[col];
                    if constexpr (EPI >= 2) v += fout[(size_t)row * N + col];
                    fout[(size_t)row * N + col] = v;
                    if constexpr (EPI == 3) outb[(size_t)row * N + col] = f2bf(v);
                }
            }
}

// ---------------- GEGLU MFMA: both halves of tn3 @ wg, fused exact GELU, bf16 out --------
// BM=128, BN=64 per half (cols n0.. and 2048+n0..), 4 waves 2x2, per-wave 64x32 per half.
__global__ __launch_bounds__(256) void geglu_mfma(const u16* __restrict__ A,
                                                  const u16* __restrict__ WgT,  // [4096][512]
                                                  const float* __restrict__ bg,
                                                  u16* __restrict__ ag) {
    __shared__ short As[128 * 32];
    __shared__ short Bs1[64 * 32];
    __shared__ short Bs2[64 * 32];
    const int K = 512;
    int tid = threadIdx.x;
    int m0 = blockIdx.y * 128, n0 = blockIdx.x * 64;
    int wave = tid >> 6, lane = tid & 63;
    int wr = wave >> 1, wc = wave & 1;
    int l15 = lane & 15, l4 = lane >> 4;

    f32x4 zero4 = {0.f, 0.f, 0.f, 0.f};
    f32x4 accA[4][2], accG[4][2];
#pragma unroll
    for (int i = 0; i < 4; i++) { accA[i][0] = zero4; accA[i][1] = zero4; accG[i][0] = zero4; accG[i][1] = zero4; }

    int srow = tid >> 1;
    int se   = (tid & 1) * 16;
    int brow = tid >> 2;
    int bqe  = (tid & 3) * 8;

    int4 ra0, ra1, rb1, rb2;
    {
        const u16* pa = A + (size_t)(m0 + srow) * K + se;
        ra0 = *(const int4*)pa; ra1 = *(const int4*)(pa + 8);
        rb1 = *(const int4*)(WgT + (size_t)(n0 + brow) * K + bqe);
        rb2 = *(const int4*)(WgT + (size_t)(2048 + n0 + brow) * K + bqe);
    }
    for (int kt = 0; kt < K; kt += 32) {
        __syncthreads();
        *(int4*)&As[srow * 32 + se]     = ra0;
        *(int4*)&As[srow * 32 + se + 8] = ra1;
        *(int4*)&Bs1[brow * 32 + bqe]   = rb1;
        *(int4*)&Bs2[brow * 32 + bqe]   = rb2;
        __syncthreads();
        int kn = kt + 32;
        if (kn < K) {
            const u16* pa = A + (size_t)(m0 + srow) * K + kn + se;
            ra0 = *(const int4*)pa; ra1 = *(const int4*)(pa + 8);
            rb1 = *(const int4*)(WgT + (size_t)(n0 + brow) * K + kn + bqe);
            rb2 = *(const int4*)(WgT + (size_t)(2048 + n0 + brow) * K + kn + bqe);
        }
        bf16x8 af[4], b1[2], b2[2];
#pragma unroll
        for (int mi = 0; mi < 4; mi++)
            af[mi] = *(const bf16x8*)&As[(wr * 64 + mi * 16 + l15) * 32 + l4 * 8];
#pragma unroll
        for (int nj = 0; nj < 2; nj++) {
            b1[nj] = *(const bf16x8*)&Bs1[(wc * 32 + nj * 16 + l15) * 32 + l4 * 8];
            b2[nj] = *(const bf16x8*)&Bs2[(wc * 32 + nj * 16 + l15) * 32 + l4 * 8];
        }
#pragma unroll
        for (int mi = 0; mi < 4; mi++)
#pragma unroll
            for (int nj = 0; nj < 2; nj++) {
                accA[mi][nj] = __builtin_amdgcn_mfma_f32_16x16x32_bf16(af[mi], b1[nj], accA[mi][nj], 0, 0, 0);
                accG[mi][nj] = __builtin_amdgcn_mfma_f32_16x16x32_bf16(af[mi], b2[nj], accG[mi][nj], 0, 0, 0);
            }
    }

#pragma unroll
    for (int mi = 0; mi < 4; mi++)
#pragma unroll
        for (int nj = 0; nj < 2; nj++)
#pragma unroll
            for (int r = 0; r < 4; r++) {
                int row = m0 + wr * 64 + mi * 16 + l4 * 4 + r;
                int col = n0 + wc * 32 + nj * 16 + l15;
                float a = accA[mi][nj][r] + bg[col];
                float g = accG[mi][nj][r] + bg[2048 + col];
                float ge = 0.5f * g * (1.0f + erff(g * 0.70710678118654752f));
                ag[(size_t)row * 2048 + col] = f2bf(a * ge);
            }
}

// ---------------- Flash attention (bf16 in/out, fp32 compute, LDS-tiled) ----------------
__global__ __launch_bounds__(256) void flash_attn(const u16* __restrict__ q,
                                                  const u16* __restrict__ k,
                                                  const u16* __restrict__ v,
                                                  u16* __restrict__ o) {
    __shared__ float Qs[64][68];
    __shared__ float Ks[64][68];
    __shared__ float Vs[64][68];
    __shared__ float Ps[64][68];
    const int tid = threadIdx.x;
    const int h = blockIdx.y, b = blockIdx.z;
    const int q0 = blockIdx.x * 64;
    const size_t hb = (size_t)b * Ss * Cch + (size_t)h * DHh;

    const int g  = tid >> 4;
    const int c  = tid & 15;
    const int qg = g * 4;

    {
        int r = tid >> 2, c4 = (tid & 3) * 16;
        const u16* src = q + hb + (size_t)(q0 + r) * Cch + c4;
        float f[8];
        bf8f(src, f);
#pragma unroll
        for (int e = 0; e < 8; e++) Qs[r][c4 + e] = f[e];
        bf8f(src + 8, f);
#pragma unroll
        for (int e = 0; e < 8; e++) Qs[r][c4 + 8 + e] = f[e];
    }

    float m_[4], l_[4], o_[4][4];
#pragma unroll
    for (int i = 0; i < 4; i++) {
        m_[i] = -3.0e38f; l_[i] = 0.f;
#pragma unroll
        for (int j = 0; j < 4; j++) o_[i][j] = 0.f;
    }

    for (int t0 = 0; t0 < Ss; t0 += 64) {
        __syncthreads();
        {
            int r = tid >> 2, c4 = (tid & 3) * 16;
            const u16* ksrc = k + hb + (size_t)(t0 + r) * Cch + c4;
            const u16* vsrc = v + hb + (size_t)(t0 + r) * Cch + c4;
            float f[8];
            bf8f(ksrc, f);
#pragma unroll
            for (int e = 0; e < 8; e++) Ks[r][c4 + e] = f[e];
            bf8f(ksrc + 8, f);
#pragma unroll
            for (int e = 0; e < 8; e++) Ks[r][c4 + 8 + e] = f[e];
            bf8f(vsrc, f);
#pragma unroll
            for (int e = 0; e < 8; e++) Vs[r][c4 + e] = f[e];
            bf8f(vsrc + 8, f);
#pragma unroll
            for (int e = 0; e < 8; e++) Vs[r][c4 + 8 + e] = f[e];
        }
        __syncthreads();

        float s_[4][4];
#pragma unroll
        for (int i = 0; i < 4; i++)
#pragma unroll
            for (int j = 0; j < 4; j++) s_[i][j] = 0.f;
        for (int kk = 0; kk < 64; kk += 4) {
            float4 qv[4], kv[4];
#pragma unroll
            for (int i = 0; i < 4; i++) qv[i] = *(const float4*)&Qs[qg + i][kk];
#pragma unroll
            for (int j = 0; j < 4; j++) kv[j] = *(const float4*)&Ks[c + 16 * j][kk];
#pragma unroll
            for (int i = 0; i < 4; i++)
#pragma unroll
                for (int j = 0; j < 4; j++) {
                    s_[i][j] = fmaf(qv[i].x, kv[j].x, s_[i][j]);
                    s_[i][j] = fmaf(qv[i].y, kv[j].y, s_[i][j]);
                    s_[i][j] = fmaf(qv[i].z, kv[j].z, s_[i][j]);
                    s_[i][j] = fmaf(qv[i].w, kv[j].w, s_[i][j]);
                }
        }

#pragma unroll
        for (int i = 0; i < 4; i++) {
#pragma unroll
            for (int j = 0; j < 4; j++) s_[i][j] *= 0.125f;
            float tm = fmaxf(fmaxf(s_[i][0], s_[i][1]), fmaxf(s_[i][2], s_[i][3]));
            tm = fmaxf(tm, __shfl_xor(tm, 1));
            tm = fmaxf(tm, __shfl_xor(tm, 2));
            tm = fmaxf(tm, __shfl_xor(tm, 4));
            tm = fmaxf(tm, __shfl_xor(tm, 8));
            float nm = fmaxf(m_[i], tm);
            float sc = __expf(m_[i] - nm);
            m_[i] = nm;
            float rs = 0.f;
#pragma unroll
            for (int j = 0; j < 4; j++) {
                float p = __expf(s_[i][j] - nm);
                Ps[qg + i][c + 16 * j] = p;
                rs += p;
            }
            rs += __shfl_xor(rs, 1);
            rs += __shfl_xor(rs, 2);
            rs += __shfl_xor(rs, 4);
            rs += __shfl_xor(rs, 8);
            l_[i] = l_[i] * sc + rs;
#pragma unroll
            for (int j = 0; j < 4; j++) o_[i][j] *= sc;
        }
        __syncthreads();

        for (int tt = 0; tt < 64; tt += 4) {
            float4 vv[4];
#pragma unroll
            for (int u = 0; u < 4; u++) vv[u] = *(const float4*)&Vs[tt + u][c * 4];
#pragma unroll
            for (int i = 0; i < 4; i++) {
                float4 p4 = *(const float4*)&Ps[qg + i][tt];
                o_[i][0] = fmaf(p4.x, vv[0].x, o_[i][0]);
                o_[i][1] = fmaf(p4.x, vv[0].y, o_[i][1]);
                o_[i][2] = fmaf(p4.x, vv[0].z, o_[i][2]);
                o_[i][3] = fmaf(p4.x, vv[0].w, o_[i][3]);
                o_[i][0] = fmaf(p4.y, vv[1].x, o_[i][0]);
                o_[i][1] = fmaf(p4.y, vv[1].y, o_[i][1]);
                o_[i][2] = fmaf(p4.y, vv[1].z, o_[i][2]);
                o_[i][3] = fmaf(p4.y, vv[1].w, o_[i][3]);
                o_[i][0] = fmaf(p4.z, vv[2].x, o_[i][0]);
                o_[i][1] = fmaf(p4.z, vv[2].y, o_[i][1]);
                o_[i][2] = fmaf(p4.z, vv[2].z, o_[i][2]);
                o_[i][3] = fmaf(p4.z, vv[2].w, o_[i][3]);
                o_[i][0] = fmaf(p4.w, vv[3].x, o_[i][0]);
                o_[i][1] = fmaf(p4.w, vv[3].y, o_[i][1]);
                o_[i][2] = fmaf(p4.w, vv[3].z, o_[i][2]);
                o_[i][3] = fmaf(p4.w, vv[3].w, o_[i][3]);
            }
        }
    }

#pragma unroll
    for (int i = 0; i < 4; i++) {
        float inv = 1.0f / l_[i];
        ushort4 r4;
        r4.x = f2bf(o_[i][0] * inv);
        r4.y = f2bf(o_[i][1] * inv);
        r4.z = f2bf(o_[i][2] * inv);
        r4.w = f2bf(o_[i][3] * inv);
        *(ushort4*)&o[hb + (size_t)(q0 + qg + i) * Cch + c * 4] = r4;
    }
}

// ---------------- final: out(B,C,S) = tmp(B,S,C)^T + x ----------------
__global__ __launch_bounds__(256) void final_out(const float* __restrict__ tmp,
                                                 const float* __restrict__ x,
                                                 float* __restrict__ outp) {
    __shared__ float tile[32][33];
    int b = blockIdx.z, c0 = blockIdx.y * 32, s0 = blockIdx.x * 32;
    int tx = threadIdx.x, ty = threadIdx.y;
#pragma unroll
    for (int i = 0; i < 4; i++) {
        int s = s0 + ty + i * 8;
        tile[ty + i * 8][tx] = tmp[((size_t)b * Ss + s) * Cch + c0 + tx];
    }
    __syncthreads();
#pragma unroll
    for (int i = 0; i < 4; i++) {
        int c = c0 + ty + i * 8;
        size_t idx = ((size_t)b * Cch + c) * Ss + s0 + tx;
        outp[idx] = tile[tx][ty + i * 8] + x[idx];
    }
}

extern "C" void kernel_launch(void* const* d_in, const int* in_sizes, int n_in,
                              void* d_out, int out_size, void* d_ws, size_t ws_size,
                              hipStream_t stream) {
    (void)in_sizes; (void)n_in; (void)out_size; (void)ws_size;
    const float* x      = (const float*)d_in[0];
    const float* gn_w   = (const float*)d_in[1];
    const float* gn_b   = (const float*)d_in[2];
    const float* pin_w  = (const float*)d_in[3];
    const float* pin_b  = (const float*)d_in[4];
    const float* ln1_w  = (const float*)d_in[5];
    const float* ln1_b  = (const float*)d_in[6];
    const float* wq     = (const float*)d_in[7];
    const float* wk     = (const float*)d_in[8];
    const float* wv     = (const float*)d_in[9];
    const float* wo     = (const float*)d_in[10];
    const float* bo     = (const float*)d_in[11];
    const float* ln3_w  = (const float*)d_in[12];
    const float* ln3_b  = (const float*)d_in[13];
    const float* wg     = (const float*)d_in[14];
    const float* bg     = (const float*)d_in[15];
    const float* wd     = (const float*)d_in[16];
    const float* bd     = (const float*)d_in[17];
    const float* pout_w = (const float*)d_in[18];
    const float* pout_b = (const float*)d_in[19];
    float* out = (float*)d_out;

    // ---- workspace layout (bytes) ----
    char* W = (char*)d_ws;
    float* t_f32   = (float*)W;                                   // 33.55 MB
    float* tmp_f32 = (float*)(W + 33554432);                      // 33.55 MB
    u16* qb    = (u16*)(W + 67108864);                            // 16.78 MB
    u16* kb    = qb + 8388608;
    u16* vb    = kb + 8388608;
    u16* attnb = vb + 8388608;
    u16* Xb    = attnb + 8388608;                                 // 16.78 MB
    float* stats = (float*)(W + 67108864 + 5ull * 16777216);      // 1 KB
    u16* wbase = (u16*)(W + 67108864 + 5ull * 16777216 + 1024);
    u16* pinB  = wbase;                 // 512*512  (already [N][K])
    u16* poutB = pinB  + 262144;
    u16* wqT   = poutB + 262144;        // [512][512] transposed
    u16* wkT   = wqT   + 262144;
    u16* wvT   = wkT   + 262144;
    u16* woT   = wvT   + 262144;
    u16* wgT   = woT   + 262144;        // [4096][512]
    u16* wdT   = wgT   + 2097152;       // [512][2048]
    u16* ag    = qb;                    // R x 2048 bf16, aliases qb..attnb (dead by then)

    dim3 tb(32, 8);

    // stats + weight prep
    gn_stats<<<128, 256, 0, stream>>>(x, stats);
    conv_bf16<<<256, 256, 0, stream>>>(pin_w,  pinB,  262144);
    conv_bf16<<<256, 256, 0, stream>>>(pout_w, poutB, 262144);
    convT_bf16<<<dim3(16, 16),  tb, 0, stream>>>(wq, wqT, 512, 512);
    convT_bf16<<<dim3(16, 16),  tb, 0, stream>>>(wk, wkT, 512, 512);
    convT_bf16<<<dim3(16, 16),  tb, 0, stream>>>(wv, wvT, 512, 512);
    convT_bf16<<<dim3(16, 16),  tb, 0, stream>>>(wo, woT, 512, 512);
    convT_bf16<<<dim3(128, 16), tb, 0, stream>>>(wg, wgT, 512, 4096);
    convT_bf16<<<dim3(16, 64),  tb, 0, stream>>>(wd, wdT, 2048, 512);

    // h = GN(x) transposed -> Xb (bf16)
    gn_apply_t_bf<<<dim3(32, 16, 16), tb, 0, stream>>>(x, stats, gn_w, gn_b, Xb);

    // t = h @ pin_w^T + pin_b -> t_f32
    mfma_gemm<1><<<dim3(4, 128), 256, 0, stream>>>(Xb, pinB, pin_b, t_f32, nullptr, 512, 512);
    // tn = ln1(t) -> Xb
    layer_norm_rows_bf<<<16384, 256, 0, stream>>>(t_f32, ln1_w, ln1_b, Xb);
    // q, k, v (bf16 out)
    mfma_gemm<0><<<dim3(4, 128), 256, 0, stream>>>(Xb, wqT, nullptr, nullptr, qb, 512, 512);
    mfma_gemm<0><<<dim3(4, 128), 256, 0, stream>>>(Xb, wkT, nullptr, nullptr, kb, 512, 512);
    mfma_gemm<0><<<dim3(4, 128), 256, 0, stream>>>(Xb, wvT, nullptr, nullptr, vb, 512, 512);
    // attention -> attnb (bf16)
    flash_attn<<<dim3(16, 8, 16), 256, 0, stream>>>(qb, kb, vb, attnb);
    // t += attn @ wo + bo (in-place on t_f32)
    mfma_gemm<2><<<dim3(4, 128), 256, 0, stream>>>(attnb, woT, bo, t_f32, nullptr, 512, 512);
    // tn3 = ln3(t) -> Xb
    layer_norm_rows_bf<<<16384, 256, 0, stream>>>(t_f32, ln3_w, ln3_b, Xb);
    // ag = a * gelu(g) (bf16), aliases q/k/v/attn space
    geglu_mfma<<<dim3(32, 128), 256, 0, stream>>>(Xb, wgT, bg, ag);
    // t += ag @ wd + bd (in-place), plus bf16 copy of new t -> Xb
    mfma_gemm<3><<<dim3(4, 128), 256, 0, stream>>>(ag, wdT, bd, t_f32, Xb, 2048, 512);
    // tmp = t @ pout_w^T + pout_b -> tmp_f32
    mfma_gemm<1><<<dim3(4, 128), 256, 0, stream>>>(Xb, poutB, pout_b, tmp_f32, nullptr, 512, 512);
    // out = tmp^T + x
    final_out<<<dim3(32, 16, 16), tb, 0, stream>>>(tmp_f32, x, out);
}

// Round 11
// 558.618 us; speedup vs baseline: 12.8230x; 1.7912x over previous
//
#include <hip/hip_runtime.h>
#include <hip/hip_bf16.h>
#include <math.h>

typedef unsigned short u16;
typedef __attribute__((ext_vector_type(8))) short bf16x8;
typedef __attribute__((ext_vector_type(4))) float f32x4;

#define Bb 16
#define Cch 512
#define Ss 1024
#define NHh 8
#define DHh 64
#define CPG 64
#define EPSV 1e-5f
#define R_TOTAL (Bb*Ss)   // 16384

__device__ inline u16 f2bf(float f) {
    unsigned int u = __float_as_uint(f);
    unsigned int r = (u + 0x7fffu + ((u >> 16) & 1u)) >> 16;
    return (u16)r;
}

// ---------------- GroupNorm stats ----------------
__global__ __launch_bounds__(256) void gn_stats(const float* __restrict__ x,
                                                float* __restrict__ stats) {
    int bg = blockIdx.x;
    int b = bg >> 3, g = bg & 7;
    const float* base = x + ((size_t)b * Cch + (size_t)g * CPG) * Ss;
    float s = 0.f, ss = 0.f;
    for (int i = threadIdx.x; i < CPG * Ss; i += 256) {
        float v = base[i];
        s += v; ss += v * v;
    }
    for (int o = 32; o > 0; o >>= 1) { s += __shfl_down(s, o); ss += __shfl_down(ss, o); }
    __shared__ float red[2][4];
    int wid = threadIdx.x >> 6, lane = threadIdx.x & 63;
    if (lane == 0) { red[0][wid] = s; red[1][wid] = ss; }
    __syncthreads();
    if (threadIdx.x == 0) {
        float S1 = red[0][0] + red[0][1] + red[0][2] + red[0][3];
        float S2 = red[1][0] + red[1][1] + red[1][2] + red[1][3];
        const float inv_n = 1.0f / (CPG * Ss);
        float mu = S1 * inv_n;
        float var = S2 * inv_n - mu * mu;
        stats[bg * 2]     = mu;
        stats[bg * 2 + 1] = rsqrtf(var + EPSV);
    }
}

// ---------------- GroupNorm apply + transpose -> bf16 (B,S,C) ----------------
__global__ __launch_bounds__(256) void gn_apply_t_bf(const float* __restrict__ x,
                                                     const float* __restrict__ stats,
                                                     const float* __restrict__ gw,
                                                     const float* __restrict__ gb,
                                                     u16* __restrict__ ht) {
    __shared__ float tile[32][33];
    int b  = blockIdx.z;
    int c0 = blockIdx.y * 32;
    int s0 = blockIdx.x * 32;
    int tx = threadIdx.x, ty = threadIdx.y;
#pragma unroll
    for (int i = 0; i < 4; i++) {
        int c = c0 + ty + i * 8;
        int g = c >> 6;
        float mu = stats[(b * 8 + g) * 2];
        float rs = stats[(b * 8 + g) * 2 + 1];
        float v = x[((size_t)b * Cch + c) * Ss + s0 + tx];
        tile[ty + i * 8][tx] = (v - mu) * rs * gw[c] + gb[c];
    }
    __syncthreads();
#pragma unroll
    for (int i = 0; i < 4; i++) {
        int s = s0 + ty + i * 8;
        ht[((size_t)b * Ss + s) * Cch + c0 + tx] = f2bf(tile[tx][ty + i * 8]);
    }
}

// ---------------- fp32 -> bf16 straight convert ----------------
__global__ __launch_bounds__(256) void conv_bf16(const float* __restrict__ in,
                                                 u16* __restrict__ outp, int n) {
    for (int i = blockIdx.x * 256 + threadIdx.x; i < n; i += gridDim.x * 256)
        outp[i] = f2bf(in[i]);
}

// ---------------- transpose + convert: in (R x C) fp32 -> out (C x R) bf16 ----------------
__global__ __launch_bounds__(256) void convT_bf16(const float* __restrict__ in,
                                                  u16* __restrict__ outp, int R, int C) {
    __shared__ float tile[32][33];
    int c0 = blockIdx.x * 32, r0 = blockIdx.y * 32;
    int tx = threadIdx.x, ty = threadIdx.y;
#pragma unroll
    for (int i = 0; i < 4; i++)
        tile[ty + i * 8][tx] = in[(size_t)(r0 + ty + i * 8) * C + c0 + tx];
    __syncthreads();
#pragma unroll
    for (int i = 0; i < 4; i++)
        outp[(size_t)(c0 + ty + i * 8) * R + r0 + tx] = f2bf(tile[tx][ty + i * 8]);
}

// ---------------- LayerNorm rows (fp32 in, bf16 out) ----------------
__global__ __launch_bounds__(256) void layer_norm_rows_bf(const float* __restrict__ in,
                                                          const float* __restrict__ w,
                                                          const float* __restrict__ bb,
                                                          u16* __restrict__ outp) {
    int row = blockIdx.x;
    const float* p = in + (size_t)row * Cch;
    float v0 = p[threadIdx.x], v1 = p[threadIdx.x + 256];
    float s = v0 + v1, ss = v0 * v0 + v1 * v1;
    for (int o = 32; o > 0; o >>= 1) { s += __shfl_down(s, o); ss += __shfl_down(ss, o); }
    __shared__ float red[2][4];
    __shared__ float mu_s, rs_s;
    int wid = threadIdx.x >> 6, lane = threadIdx.x & 63;
    if (lane == 0) { red[0][wid] = s; red[1][wid] = ss; }
    __syncthreads();
    if (threadIdx.x == 0) {
        float S1 = red[0][0] + red[0][1] + red[0][2] + red[0][3];
        float S2 = red[1][0] + red[1][1] + red[1][2] + red[1][3];
        float mu = S1 * (1.0f / Cch);
        float var = S2 * (1.0f / Cch) - mu * mu;
        mu_s = mu; rs_s = rsqrtf(var + EPSV);
    }
    __syncthreads();
    float mu = mu_s, rs = rs_s;
    outp[(size_t)row * Cch + threadIdx.x]       = f2bf((v0 - mu) * rs * w[threadIdx.x] + bb[threadIdx.x]);
    outp[(size_t)row * Cch + threadIdx.x + 256] = f2bf((v1 - mu) * rs * w[threadIdx.x + 256] + bb[threadIdx.x + 256]);
}

// ---------------- MFMA GEMM: out(MxN) = A(MxK bf16) @ Bt(NxK bf16)^T ----------------
// 128x128 tile, BK=32, 256 thr = 4 waves (2x2), per-wave 64x64 = 4x4 16x16 frags.
// EPI: 0 = store bf16; 1 = fp32 +bias; 2 = fp32 +bias+res(inplace);
//      3 = EPI2 + bf16 copy; 4 = bf16 store TRANSPOSED per-head: out[((b*8+h)*64+d)*1024+s]
template<int EPI>
__global__ __launch_bounds__(256) void mfma_gemm(const u16* __restrict__ A,
                                                 const u16* __restrict__ Bt,
                                                 const float* __restrict__ bias,
                                                 float* __restrict__ fout,
                                                 u16* __restrict__ outb,
                                                 int K, int N) {
    __shared__ short As[128 * 32];
    __shared__ short Bs[128 * 32];
    int tid = threadIdx.x;
    int m0 = blockIdx.y * 128, n0 = blockIdx.x * 128;
    int wave = tid >> 6, lane = tid & 63;
    int wr = wave >> 1, wc = wave & 1;
    int l15 = lane & 15, l4 = lane >> 4;

    f32x4 zero4 = {0.f, 0.f, 0.f, 0.f};
    f32x4 acc[4][4];
#pragma unroll
    for (int i = 0; i < 4; i++)
#pragma unroll
        for (int j = 0; j < 4; j++) acc[i][j] = zero4;

    int srow = tid >> 1;
    int se   = (tid & 1) * 16;

    int4 ra0, ra1, rb0, rb1;
    {
        const u16* pa = A  + (size_t)(m0 + srow) * K + se;
        ra0 = *(const int4*)pa; ra1 = *(const int4*)(pa + 8);
        const u16* pb = Bt + (size_t)(n0 + srow) * K + se;
        rb0 = *(const int4*)pb; rb1 = *(const int4*)(pb + 8);
    }
    for (int kt = 0; kt < K; kt += 32) {
        __syncthreads();
        *(int4*)&As[srow * 32 + se]     = ra0;
        *(int4*)&As[srow * 32 + se + 8] = ra1;
        *(int4*)&Bs[srow * 32 + se]     = rb0;
        *(int4*)&Bs[srow * 32 + se + 8] = rb1;
        __syncthreads();
        int kn = kt + 32;
        if (kn < K) {
            const u16* pa = A  + (size_t)(m0 + srow) * K + kn + se;
            ra0 = *(const int4*)pa; ra1 = *(const int4*)(pa + 8);
            const u16* pb = Bt + (size_t)(n0 + srow) * K + kn + se;
            rb0 = *(const int4*)pb; rb1 = *(const int4*)(pb + 8);
        }
        bf16x8 af[4], bfr[4];
#pragma unroll
        for (int mi = 0; mi < 4; mi++)
            af[mi] = *(const bf16x8*)&As[(wr * 64 + mi * 16 + l15) * 32 + l4 * 8];
#pragma unroll
        for (int nj = 0; nj < 4; nj++)
            bfr[nj] = *(const bf16x8*)&Bs[(wc * 64 + nj * 16 + l15) * 32 + l4 * 8];
#pragma unroll
        for (int mi = 0; mi < 4; mi++)
#pragma unroll
            for (int nj = 0; nj < 4; nj++)
                acc[mi][nj] = __builtin_amdgcn_mfma_f32_16x16x32_bf16(af[mi], bfr[nj], acc[mi][nj], 0, 0, 0);
    }

    if constexpr (EPI == 4) {
#pragma unroll
        for (int mi = 0; mi < 4; mi++)
#pragma unroll
            for (int nj = 0; nj < 4; nj++) {
                int row0 = m0 + wr * 64 + mi * 16 + l4 * 4;    // token base (4-aligned)
                int col  = n0 + wc * 64 + nj * 16 + l15;       // channel
                int bI = row0 >> 10, sI = row0 & 1023;
                int hI = col >> 6,  dI = col & 63;
                ushort4 r4;
                r4.x = f2bf(acc[mi][nj][0]);
                r4.y = f2bf(acc[mi][nj][1]);
                r4.z = f2bf(acc[mi][nj][2]);
                r4.w = f2bf(acc[mi][nj][3]);
                *(ushort4*)&outb[((size_t)(bI * 8 + hI) * 64 + dI) * 1024 + sI] = r4;
            }
        return;
    }

#pragma unroll
    for (int mi = 0; mi < 4; mi++)
#pragma unroll
        for (int nj = 0; nj < 4; nj++)
#pragma unroll
            for (int r = 0; r < 4; r++) {
                int row = m0 + wr * 64 + mi * 16 + l4 * 4 + r;
                int col = n0 + wc * 64 + nj * 16 + l15;
                float v = acc[mi][nj][r];
                if constexpr (EPI == 0) {
                    outb[(size_t)row * N + col] = f2bf(v);
                } else {
                    v += bias[col];
                    if constexpr (EPI >= 2) v += fout[(size_t)row * N + col];
                    fout[(size_t)row * N + col] = v;
                    if constexpr (EPI == 3) outb[(size_t)row * N + col] = f2bf(v);
                }
            }
}

// ---------------- GEGLU MFMA: both halves of tn3 @ wg, fused exact GELU, bf16 out --------
__global__ __launch_bounds__(256) void geglu_mfma(const u16* __restrict__ A,
                                                  const u16* __restrict__ WgT,  // [4096][512]
                                                  const float* __restrict__ bg,
                                                  u16* __restrict__ ag) {
    __shared__ short As[128 * 32];
    __shared__ short Bs1[64 * 32];
    __shared__ short Bs2[64 * 32];
    const int K = 512;
    int tid = threadIdx.x;
    int m0 = blockIdx.y * 128, n0 = blockIdx.x * 64;
    int wave = tid >> 6, lane = tid & 63;
    int wr = wave >> 1, wc = wave & 1;
    int l15 = lane & 15, l4 = lane >> 4;

    f32x4 zero4 = {0.f, 0.f, 0.f, 0.f};
    f32x4 accA[4][2], accG[4][2];
#pragma unroll
    for (int i = 0; i < 4; i++) { accA[i][0] = zero4; accA[i][1] = zero4; accG[i][0] = zero4; accG[i][1] = zero4; }

    int srow = tid >> 1;
    int se   = (tid & 1) * 16;
    int brow = tid >> 2;
    int bqe  = (tid & 3) * 8;

    int4 ra0, ra1, rb1, rb2;
    {
        const u16* pa = A + (size_t)(m0 + srow) * K + se;
        ra0 = *(const int4*)pa; ra1 = *(const int4*)(pa + 8);
        rb1 = *(const int4*)(WgT + (size_t)(n0 + brow) * K + bqe);
        rb2 = *(const int4*)(WgT + (size_t)(2048 + n0 + brow) * K + bqe);
    }
    for (int kt = 0; kt < K; kt += 32) {
        __syncthreads();
        *(int4*)&As[srow * 32 + se]     = ra0;
        *(int4*)&As[srow * 32 + se + 8] = ra1;
        *(int4*)&Bs1[brow * 32 + bqe]   = rb1;
        *(int4*)&Bs2[brow * 32 + bqe]   = rb2;
        __syncthreads();
        int kn = kt + 32;
        if (kn < K) {
            const u16* pa = A + (size_t)(m0 + srow) * K + kn + se;
            ra0 = *(const int4*)pa; ra1 = *(const int4*)(pa + 8);
            rb1 = *(const int4*)(WgT + (size_t)(n0 + brow) * K + kn + bqe);
            rb2 = *(const int4*)(WgT + (size_t)(2048 + n0 + brow) * K + kn + bqe);
        }
        bf16x8 af[4], b1[2], b2[2];
#pragma unroll
        for (int mi = 0; mi < 4; mi++)
            af[mi] = *(const bf16x8*)&As[(wr * 64 + mi * 16 + l15) * 32 + l4 * 8];
#pragma unroll
        for (int nj = 0; nj < 2; nj++) {
            b1[nj] = *(const bf16x8*)&Bs1[(wc * 32 + nj * 16 + l15) * 32 + l4 * 8];
            b2[nj] = *(const bf16x8*)&Bs2[(wc * 32 + nj * 16 + l15) * 32 + l4 * 8];
        }
#pragma unroll
        for (int mi = 0; mi < 4; mi++)
#pragma unroll
            for (int nj = 0; nj < 2; nj++) {
                accA[mi][nj] = __builtin_amdgcn_mfma_f32_16x16x32_bf16(af[mi], b1[nj], accA[mi][nj], 0, 0, 0);
                accG[mi][nj] = __builtin_amdgcn_mfma_f32_16x16x32_bf16(af[mi], b2[nj], accG[mi][nj], 0, 0, 0);
            }
    }

#pragma unroll
    for (int mi = 0; mi < 4; mi++)
#pragma unroll
        for (int nj = 0; nj < 2; nj++)
#pragma unroll
            for (int r = 0; r < 4; r++) {
                int row = m0 + wr * 64 + mi * 16 + l4 * 4 + r;
                int col = n0 + wc * 32 + nj * 16 + l15;
                float a = accA[mi][nj][r] + bg[col];
                float g = accG[mi][nj][r] + bg[2048 + col];
                float ge = 0.5f * g * (1.0f + erff(g * 0.70710678118654752f));
                ag[(size_t)row * 2048 + col] = f2bf(a * ge);
            }
}

// ---------------- MFMA flash attention ----------------
// Block = 256 thr (4 waves), 64 queries of one (b,h); KV tiles of 64.
// Wave wq owns q rows [wq*16, wq*16+16). QK^T: A=Q[64][64], Bt=K[64][64].
// PV: A=P (LDS round-trip, wave-private rows), Bt=Vt[d][t] (V pre-transposed in global).
// LDS strides: 72 (Qs/Ks/Vt: b128 row-reads 2-way = free), 68 (Ps: conflict-free 2B writes).
__global__ __launch_bounds__(256) void flash_attn_mfma(const u16* __restrict__ q,
                                                       const u16* __restrict__ k,
                                                       const u16* __restrict__ vt,  // [b][h][64][1024]
                                                       u16* __restrict__ o) {
    __shared__ u16 Qs[64 * 72];
    __shared__ u16 Ks[64 * 72];
    __shared__ u16 Vt[64 * 72];
    __shared__ u16 Ps[64 * 68];
    const int tid = threadIdx.x;
    const int h = blockIdx.y, b = blockIdx.z;
    const int q0 = blockIdx.x * 64;
    const size_t hb  = (size_t)b * Ss * Cch + (size_t)h * DHh;
    const size_t vhb = ((size_t)(b * NHh + h) * DHh) * Ss;

    const int wq = tid >> 6;
    const int lane = tid & 63;
    const int l15 = lane & 15, l4 = lane >> 4;

    // stage Q (64x64), coalesced 32B/thread
    {
        int r = tid >> 2, c4 = (tid & 3) * 16;
        const u16* src = q + hb + (size_t)(q0 + r) * Cch + c4;
        *(int4*)&Qs[r * 72 + c4]     = *(const int4*)src;
        *(int4*)&Qs[r * 72 + c4 + 8] = *(const int4*)(src + 8);
    }

    f32x4 zero4 = {0.f, 0.f, 0.f, 0.f};
    f32x4 oacc[4];
    float m_[4], l_[4];
#pragma unroll
    for (int j = 0; j < 4; j++) oacc[j] = zero4;
#pragma unroll
    for (int r = 0; r < 4; r++) { m_[r] = -1e30f; l_[r] = 0.f; }

    for (int t0 = 0; t0 < Ss; t0 += 64) {
        __syncthreads();   // prev tile's Ks/Vt reads done
        {
            int r = tid >> 2, c4 = (tid & 3) * 16;
            const u16* ksrc = k + hb + (size_t)(t0 + r) * Cch + c4;
            *(int4*)&Ks[r * 72 + c4]     = *(const int4*)ksrc;
            *(int4*)&Ks[r * 72 + c4 + 8] = *(const int4*)(ksrc + 8);
            const u16* vsrc = vt + vhb + (size_t)r * Ss + t0 + c4;
            *(int4*)&Vt[r * 72 + c4]     = *(const int4*)vsrc;
            *(int4*)&Vt[r * 72 + c4 + 8] = *(const int4*)(vsrc + 8);
        }
        __syncthreads();

        // QK^T: wave's 16 q-rows x 64 t-cols
        f32x4 sacc[4];
#pragma unroll
        for (int j = 0; j < 4; j++) sacc[j] = zero4;
#pragma unroll
        for (int ks = 0; ks < 2; ks++) {
            bf16x8 aq = *(const bf16x8*)&Qs[(wq * 16 + l15) * 72 + ks * 32 + l4 * 8];
#pragma unroll
            for (int j = 0; j < 4; j++) {
                bf16x8 bk = *(const bf16x8*)&Ks[(j * 16 + l15) * 72 + ks * 32 + l4 * 8];
                sacc[j] = __builtin_amdgcn_mfma_f32_16x16x32_bf16(aq, bk, sacc[j], 0, 0, 0);
            }
        }

        // online softmax: lane holds rows l4*4+r, cols l15+16j
#pragma unroll
        for (int r = 0; r < 4; r++) {
            float s0 = sacc[0][r] * 0.125f;
            float s1 = sacc[1][r] * 0.125f;
            float s2 = sacc[2][r] * 0.125f;
            float s3 = sacc[3][r] * 0.125f;
            float tm = fmaxf(fmaxf(s0, s1), fmaxf(s2, s3));
            tm = fmaxf(tm, __shfl_xor(tm, 1));
            tm = fmaxf(tm, __shfl_xor(tm, 2));
            tm = fmaxf(tm, __shfl_xor(tm, 4));
            tm = fmaxf(tm, __shfl_xor(tm, 8));
            float nm = fmaxf(m_[r], tm);
            float sc = __expf(m_[r] - nm);
            m_[r] = nm;
            float p0 = __expf(s0 - nm), p1 = __expf(s1 - nm);
            float p2 = __expf(s2 - nm), p3 = __expf(s3 - nm);
            int prow = (wq * 16 + l4 * 4 + r) * 68 + l15;
            Ps[prow]      = f2bf(p0);
            Ps[prow + 16] = f2bf(p1);
            Ps[prow + 32] = f2bf(p2);
            Ps[prow + 48] = f2bf(p3);
            float rs = p0 + p1 + p2 + p3;
            rs += __shfl_xor(rs, 1);
            rs += __shfl_xor(rs, 2);
            rs += __shfl_xor(rs, 4);
            rs += __shfl_xor(rs, 8);
            l_[r] = l_[r] * sc + rs;
#pragma unroll
            for (int j = 0; j < 4; j++) oacc[j][r] *= sc;
        }

        // PV: A=Ps (own rows, same-wave dep), Bt=Vt[d][t]
#pragma unroll
        for (int ks = 0; ks < 2; ks++) {
            bf16x8 pa = *(const bf16x8*)&Ps[(wq * 16 + l15) * 68 + ks * 32 + l4 * 8];
#pragma unroll
            for (int j = 0; j < 4; j++) {
                bf16x8 bv = *(const bf16x8*)&Vt[(j * 16 + l15) * 72 + ks * 32 + l4 * 8];
                oacc[j] = __builtin_amdgcn_mfma_f32_16x16x32_bf16(pa, bv, oacc[j], 0, 0, 0);
            }
        }
    }

    // finalize: O /= l, stage via Qs (wave-private rows), coalesced store
#pragma unroll
    for (int r = 0; r < 4; r++) {
        float inv = 1.0f / l_[r];
        int orow = (wq * 16 + l4 * 4 + r) * 72 + l15;
#pragma unroll
        for (int j = 0; j < 4; j++)
            Qs[orow + 16 * j] = f2bf(oacc[j][r] * inv);
    }
    __syncthreads();
    {
        int r = tid >> 2, c4 = (tid & 3) * 16;
        u16* dst = o + hb + (size_t)(q0 + r) * Cch + c4;
        *(int4*)dst       = *(const int4*)&Qs[r * 72 + c4];
        *(int4*)(dst + 8) = *(const int4*)&Qs[r * 72 + c4 + 8];
    }
}

// ---------------- final: out(B,C,S) = tmp(B,S,C)^T + x ----------------
__global__ __launch_bounds__(256) void final_out(const float* __restrict__ tmp,
                                                 const float* __restrict__ x,
                                                 float* __restrict__ outp) {
    __shared__ float tile[32][33];
    int b = blockIdx.z, c0 = blockIdx.y * 32, s0 = blockIdx.x * 32;
    int tx = threadIdx.x, ty = threadIdx.y;
#pragma unroll
    for (int i = 0; i < 4; i++) {
        int s = s0 + ty + i * 8;
        tile[ty + i * 8][tx] = tmp[((size_t)b * Ss + s) * Cch + c0 + tx];
    }
    __syncthreads();
#pragma unroll
    for (int i = 0; i < 4; i++) {
        int c = c0 + ty + i * 8;
        size_t idx = ((size_t)b * Cch + c) * Ss + s0 + tx;
        outp[idx] = tile[tx][ty + i * 8] + x[idx];
    }
}

extern "C" void kernel_launch(void* const* d_in, const int* in_sizes, int n_in,
                              void* d_out, int out_size, void* d_ws, size_t ws_size,
                              hipStream_t stream) {
    (void)in_sizes; (void)n_in; (void)out_size; (void)ws_size;
    const float* x      = (const float*)d_in[0];
    const float* gn_w   = (const float*)d_in[1];
    const float* gn_b   = (const float*)d_in[2];
    const float* pin_w  = (const float*)d_in[3];
    const float* pin_b  = (const float*)d_in[4];
    const float* ln1_w  = (const float*)d_in[5];
    const float* ln1_b  = (const float*)d_in[6];
    const float* wq     = (const float*)d_in[7];
    const float* wk     = (const float*)d_in[8];
    const float* wv     = (const float*)d_in[9];
    const float* wo     = (const float*)d_in[10];
    const float* bo     = (const float*)d_in[11];
    const float* ln3_w  = (const float*)d_in[12];
    const float* ln3_b  = (const float*)d_in[13];
    const float* wg     = (const float*)d_in[14];
    const float* bg     = (const float*)d_in[15];
    const float* wd     = (const float*)d_in[16];
    const float* bd     = (const float*)d_in[17];
    const float* pout_w = (const float*)d_in[18];
    const float* pout_b = (const float*)d_in[19];
    float* out = (float*)d_out;

    // ---- workspace layout (bytes) ----
    char* W = (char*)d_ws;
    float* t_f32   = (float*)W;                                   // 33.55 MB
    float* tmp_f32 = (float*)(W + 33554432);                      // 33.55 MB
    u16* qb    = (u16*)(W + 67108864);                            // 16.78 MB
    u16* kb    = qb + 8388608;
    u16* vb    = kb + 8388608;                                    // holds V^T [b][h][64][1024]
    u16* attnb = vb + 8388608;
    u16* Xb    = attnb + 8388608;                                 // 16.78 MB
    float* stats = (float*)(W + 67108864 + 5ull * 16777216);      // 1 KB
    u16* wbase = (u16*)(W + 67108864 + 5ull * 16777216 + 1024);
    u16* pinB  = wbase;                 // 512*512  (already [N][K])
    u16* poutB = pinB  + 262144;
    u16* wqT   = poutB + 262144;        // [512][512] transposed
    u16* wkT   = wqT   + 262144;
    u16* wvT   = wkT   + 262144;
    u16* woT   = wvT   + 262144;
    u16* wgT   = woT   + 262144;        // [4096][512]
    u16* wdT   = wgT   + 2097152;       // [512][2048]
    u16* ag    = qb;                    // R x 2048 bf16, aliases qb..attnb (dead by then)

    dim3 tb(32, 8);

    // stats + weight prep
    gn_stats<<<128, 256, 0, stream>>>(x, stats);
    conv_bf16<<<256, 256, 0, stream>>>(pin_w,  pinB,  262144);
    conv_bf16<<<256, 256, 0, stream>>>(pout_w, poutB, 262144);
    convT_bf16<<<dim3(16, 16),  tb, 0, stream>>>(wq, wqT, 512, 512);
    convT_bf16<<<dim3(16, 16),  tb, 0, stream>>>(wk, wkT, 512, 512);
    convT_bf16<<<dim3(16, 16),  tb, 0, stream>>>(wv, wvT, 512, 512);
    convT_bf16<<<dim3(16, 16),  tb, 0, stream>>>(wo, woT, 512, 512);
    convT_bf16<<<dim3(128, 16), tb, 0, stream>>>(wg, wgT, 512, 4096);
    convT_bf16<<<dim3(16, 64),  tb, 0, stream>>>(wd, wdT, 2048, 512);

    // h = GN(x) transposed -> Xb (bf16)
    gn_apply_t_bf<<<dim3(32, 16, 16), tb, 0, stream>>>(x, stats, gn_w, gn_b, Xb);

    // t = h @ pin_w^T + pin_b -> t_f32
    mfma_gemm<1><<<dim3(4, 128), 256, 0, stream>>>(Xb, pinB, pin_b, t_f32, nullptr, 512, 512);
    // tn = ln1(t) -> Xb
    layer_norm_rows_bf<<<16384, 256, 0, stream>>>(t_f32, ln1_w, ln1_b, Xb);
    // q, k (bf16), v stored TRANSPOSED per head
    mfma_gemm<0><<<dim3(4, 128), 256, 0, stream>>>(Xb, wqT, nullptr, nullptr, qb, 512, 512);
    mfma_gemm<0><<<dim3(4, 128), 256, 0, stream>>>(Xb, wkT, nullptr, nullptr, kb, 512, 512);
    mfma_gemm<4><<<dim3(4, 128), 256, 0, stream>>>(Xb, wvT, nullptr, nullptr, vb, 512, 512);
    // attention (MFMA) -> attnb (bf16)
    flash_attn_mfma<<<dim3(16, 8, 16), 256, 0, stream>>>(qb, kb, vb, attnb);
    // t += attn @ wo + bo (in-place on t_f32)
    mfma_gemm<2><<<dim3(4, 128), 256, 0, stream>>>(attnb, woT, bo, t_f32, nullptr, 512, 512);
    // tn3 = ln3(t) -> Xb
    layer_norm_rows_bf<<<16384, 256, 0, stream>>>(t_f32, ln3_w, ln3_b, Xb);
    // ag = a * gelu(g) (bf16), aliases q/k/v/attn space
    geglu_mfma<<<dim3(32, 128), 256, 0, stream>>>(Xb, wgT, bg, ag);
    // t += ag @ wd + bd (in-place), plus bf16 copy of new t -> Xb
    mfma_gemm<3><<<dim3(4, 128), 256, 0, stream>>>(ag, wdT, bd, t_f32, Xb, 2048, 512);
    // tmp = t @ pout_w^T + pout_b -> tmp_f32
    mfma_gemm<1><<<dim3(4, 128), 256, 0, stream>>>(Xb, poutB, pout_b, tmp_f32, nullptr, 512, 512);
    // out = tmp^T + x
    final_out<<<dim3(32, 16, 16), tb, 0, stream>>>(tmp_f32, x, out);
}